// Round 5
// baseline (1305.587 us; speedup 1.0000x reference)
//
#include <hip/hip_runtime.h>
#include <math.h>

#define BB 8
#define NN 1024
#define CC 16
#define SS 32
#define LLAYERS 8
#define HH 8

typedef unsigned short ushort_t;
typedef unsigned int uint_t;
using bf16x8 = __attribute__((ext_vector_type(8))) short;
using f32x4  = __attribute__((ext_vector_type(4))) float;

// Blade metadata (reference blade ordering):
// 0:() 1:(0) 2:(1) 3:(2) 4:(3) 5:(01) 6:(02) 7:(03) 8:(12) 9:(13) 10:(23)
// 11:(012) 12:(013) 13:(023) 14:(123) 15:(0123)
__constant__ int d_GRADE[16] = {0,1,1,1,1,2,2,2,2,2,2,3,3,3,3,4};
__constant__ int d_PAIR[16]  = {-1,0,-1,-1,-1,2,3,4,-1,-1,-1,8,9,10,-1,14};
// the 8 INNER (e0-free) blades in order
__constant__ int d_IB[8] = {0,2,3,4,8,9,10,14};
// blade index -> bitmask over {e0,e1,e2,e3}
__constant__ int d_I2M[16] = {0,1,2,4,8,3,5,9,6,10,12,7,11,13,14,15};
// bitmask -> blade index
__constant__ int d_M2I[16] = {0,1,2,5,3,6,8,11,4,7,9,12,10,13,14,15};

// softmax in log2 domain: fold 1/sqrt(20) * log2(e) into Q at pack time
#define QSCALE (0.22360679774997896f * 1.4426950408889634f)

__device__ __forceinline__ float gelu_tanh(float x) {
  float x3 = x * x * x;
  float inner = 0.7978845608028654f * (x + 0.044715f * x3);
  return 0.5f * x * (1.0f + tanhf(inner));
}

__device__ __forceinline__ ushort_t f2b(float f) {
  union { float f; unsigned int u; } x;
  x.f = f;
  unsigned int r = x.u + 0x7fffu + ((x.u >> 16) & 1u);  // RNE
  return (ushort_t)(r >> 16);
}

// ---------------- embed ----------------
__global__ void __launch_bounds__(256) k_embed(
    const float* __restrict__ inp, const float* __restrict__ win_mv,
    const float* __restrict__ win_ms, const float* __restrict__ win_bs,
    float* __restrict__ mv, float* __restrict__ s)
{
  int tok = blockIdx.x, t = threadIdx.x;
  float x = inp[tok * 3 + 0];
  float y = inp[tok * 3 + 1];
  float z = inp[tok * 3 + 2];
  int o = t >> 4, aa = t & 15;
  float ma = (aa == 14) ? 1.f : (aa == 13) ? -x : (aa == 12) ? y : (aa == 11) ? -z : 0.f;
  int g = d_GRADE[aa];
  float val = win_mv[o * 9 + g] * ma;
  int pr = d_PAIR[aa];
  if (pr >= 0) {
    float mp = (pr == 14) ? 1.f : 0.f;
    val += win_mv[o * 9 + 4 + g] * mp;
  }
  mv[(size_t)tok * 256 + t] = val;
  if (t < 32) s[(size_t)tok * 32 + t] = win_bs[t];
  (void)win_ms;
}

// ---------------- LN + QKV projection, 8-token tile ----------------
__global__ void __launch_bounds__(256) k_ln_qkv(
    const float* __restrict__ mv, const float* __restrict__ s,
    const float* __restrict__ wmv, const float* __restrict__ wsm,
    const float* __restrict__ wms, const float* __restrict__ wss,
    ushort_t* __restrict__ q_bf, ushort_t* __restrict__ k_bf, ushort_t* __restrict__ vT)
{
  __shared__ float pool[9600];
  float* xmv = pool;           // [8][256]
  float* xs  = pool + 2048;    // [8][32]
  float* yst = pool + 2304;    // [8][48] rows, stride 17
  float* sst = pool + 8832;    // [8][96]

  int t = threadIdx.x;
  int tok0 = blockIdx.x * 8;
  int b = tok0 >> 10, n0 = tok0 & 1023;
  int a = t & 15, og = t >> 4;
  int g = d_GRADE[a], pr = d_PAIR[a];

  // weights -> registers (loop-invariant over the 8 tokens)
  float wgq[16], wpq[16], wgk[16], wpk[16], wgv[16], wpv[16];
  #pragma unroll
  for (int i = 0; i < 16; ++i) {
    wgq[i] = wmv[(og)      * 144 + i * 9 + g];
    wgk[i] = wmv[(16 + og) * 144 + i * 9 + g];
    wgv[i] = wmv[(32 + og) * 144 + i * 9 + g];
    wpq[i] = wmv[(og)      * 144 + i * 9 + 4 + g];
    wpk[i] = wmv[(16 + og) * 144 + i * 9 + 4 + g];
    wpv[i] = wmv[(32 + og) * 144 + i * 9 + 4 + g];
  }

  // stage inputs (coalesced)
  #pragma unroll
  for (int j = 0; j < 2; ++j)
    *(float4*)&xmv[t * 4 + j * 1024] = *(const float4*)&mv[(size_t)tok0 * 256 + t * 4 + j * 1024];
  if (t < 64)
    *(float4*)&xs[t * 4] = *(const float4*)&s[(size_t)tok0 * 32 + t * 4];
  __syncthreads();

  // LN: 16 lanes per token
  if (t < 128) {
    int tk = t >> 4, ch = t & 15;
    float* xp = &xmv[tk * 256 + ch * 16];
    float4 v0 = *(float4*)&xp[0], v1 = *(float4*)&xp[4];
    float4 v2 = *(float4*)&xp[8], v3 = *(float4*)&xp[12];
    float ss = v0.x*v0.x + v0.z*v0.z + v0.w*v0.w + v1.x*v1.x
             + v2.x*v2.x + v2.y*v2.y + v2.z*v2.z + v3.z*v3.z;
    ss += __shfl_xor(ss, 1); ss += __shfl_xor(ss, 2);
    ss += __shfl_xor(ss, 4); ss += __shfl_xor(ss, 8);
    float inv = rsqrtf(ss / 16.f + 1e-6f);
    v0.x*=inv; v0.y*=inv; v0.z*=inv; v0.w*=inv;
    v1.x*=inv; v1.y*=inv; v1.z*=inv; v1.w*=inv;
    v2.x*=inv; v2.y*=inv; v2.z*=inv; v2.w*=inv;
    v3.x*=inv; v3.y*=inv; v3.z*=inv; v3.w*=inv;
    *(float4*)&xp[0] = v0; *(float4*)&xp[4] = v1;
    *(float4*)&xp[8] = v2; *(float4*)&xp[12] = v3;
    float s0 = xs[tk * 32 + ch * 2], s1 = xs[tk * 32 + ch * 2 + 1];
    float s2 = s0 * s0 + s1 * s1;
    s2 += __shfl_xor(s2, 1); s2 += __shfl_xor(s2, 2);
    s2 += __shfl_xor(s2, 4); s2 += __shfl_xor(s2, 8);
    float sinv = rsqrtf(s2 / 32.f + 1e-6f);
    xs[tk * 32 + ch * 2] = s0 * sinv;
    xs[tk * 32 + ch * 2 + 1] = s1 * sinv;
  }
  __syncthreads();

  // main projection: thread owns (q-ch og, k-ch og, v-ch og) x blade a
  for (int tk = 0; tk < 8; ++tk) {
    float y0 = 0.f, y1 = 0.f, y2 = 0.f;
    const float* xb = &xmv[tk * 256];
    #pragma unroll
    for (int i = 0; i < 16; ++i) {
      float xa_ = xb[i * 16 + a];
      y0 += wgq[i] * xa_; y1 += wgk[i] * xa_; y2 += wgv[i] * xa_;
    }
    if (pr >= 0) {
      #pragma unroll
      for (int i = 0; i < 16; ++i) {
        float xp_ = xb[i * 16 + pr];
        y0 += wpq[i] * xp_; y1 += wpk[i] * xp_; y2 += wpv[i] * xp_;
      }
    }
    yst[(tk * 48 + og) * 17 + a] = y0;
    yst[(tk * 48 + 16 + og) * 17 + a] = y1;
    yst[(tk * 48 + 32 + og) * 17 + a] = y2;
  }
  __syncthreads();

  // wsm term into blade-0 column + scalar outputs
  for (int u = t; u < 384; u += 256) {
    int tk = u / 48, o = u % 48;
    float add = 0.f;
    #pragma unroll
    for (int j = 0; j < 32; ++j) add += wsm[o * 32 + j] * xs[tk * 32 + j];
    yst[(tk * 48 + o) * 17 + 0] += add;
  }
  for (int u = t; u < 768; u += 256) {
    int tk = u / 96, o96 = u % 96;
    float yy = 0.f;
    #pragma unroll
    for (int j = 0; j < 32; ++j) yy += wss[o96 * 32 + j] * xs[tk * 32 + j];
    #pragma unroll
    for (int i = 0; i < 16; ++i) yy += wms[o96 * 16 + i] * xmv[tk * 256 + i * 16];
    sst[tk * 96 + o96] = yy;
  }
  __syncthreads();

  // pack q/k rows (64B vector stores)
  if (t < 128) {
    int isK = t >> 6;
    int r = t & 63;
    int tk = r >> 3, h = r & 7;
    float scale = isK ? 1.f : QSCALE;
    const float* base = &yst[(tk * 48 + isK * 16) * 17];
    ushort_t tmp[32];
    #pragma unroll
    for (int j = 0; j < 8; ++j) {
      int blade = d_IB[j];
      tmp[j]     = f2b(base[(2 * h)     * 17 + blade] * scale);
      tmp[8 + j] = f2b(base[(2 * h + 1) * 17 + blade] * scale);
    }
    #pragma unroll
    for (int d = 0; d < 4; ++d)
      tmp[16 + d] = f2b(sst[tk * 96 + isK * 32 + h * 4 + d] * scale);
    #pragma unroll
    for (int j2 = 20; j2 < 32; ++j2) tmp[j2] = 0;
    uint_t out[16];
    #pragma unroll
    for (int j3 = 0; j3 < 16; ++j3)
      out[j3] = (uint_t)tmp[2 * j3] | ((uint_t)tmp[2 * j3 + 1] << 16);
    ushort_t* dst = (isK ? k_bf : q_bf) + ((size_t)(b * 8 + h) * 1024 + n0 + tk) * 32;
    *(uint4*)(dst +  0) = make_uint4(out[0],  out[1],  out[2],  out[3]);
    *(uint4*)(dst +  8) = make_uint4(out[4],  out[5],  out[6],  out[7]);
    *(uint4*)(dst + 16) = make_uint4(out[8],  out[9],  out[10], out[11]);
    *(uint4*)(dst + 24) = make_uint4(out[12], out[13], out[14], out[15]);
  }
  // pack vT mv-dim rows (16B per row of 8 tokens)
  {
    int h = t >> 5, dim = t & 31;
    int ch = 2 * h + (dim >> 4), blade = dim & 15;
    uint_t ov[4];
    #pragma unroll
    for (int tk = 0; tk < 8; ++tk) {
      ushort_t bv = f2b(yst[(tk * 48 + 32 + ch) * 17 + blade]);
      if (tk & 1) ov[tk >> 1] |= ((uint_t)bv) << 16; else ov[tk >> 1] = bv;
    }
    ushort_t* dst = vT + ((size_t)(b * 8 + h) * 48 + dim) * 1024 + n0;
    *(uint4*)dst = make_uint4(ov[0], ov[1], ov[2], ov[3]);
  }
  // pack vT scalar-dim rows
  if (t < 32) {
    int h = t >> 2, d = t & 3;
    uint_t ov[4];
    #pragma unroll
    for (int tk = 0; tk < 8; ++tk) {
      ushort_t bv = f2b(sst[tk * 96 + 64 + h * 4 + d]);
      if (tk & 1) ov[tk >> 1] |= ((uint_t)bv) << 16; else ov[tk >> 1] = bv;
    }
    ushort_t* dst = vT + ((size_t)(b * 8 + h) * 48 + 32 + d) * 1024 + n0;
    *(uint4*)dst = make_uint4(ov[0], ov[1], ov[2], ov[3]);
  }
  // ones row (vdim 36): l = sum(P) falls out of the PV MFMA for free
  if (t < 8) {
    ushort_t* dst = vT + ((size_t)(b * 8 + t) * 48 + 36) * 1024 + n0;
    *(uint4*)dst = make_uint4(0x3F803F80u, 0x3F803F80u, 0x3F803F80u, 0x3F803F80u);
  }
}

// ---------------- attention: bf16 MFMA flash, no-max softmax ----------------
// grid = 16 q-tiles x 64 (b,h); bx&63 = bh so all 16 tiles of one head share an XCD.
// p = exp2(s) directly (log2-domain scores, bounded by LN), O/l accumulate
// unnormalized in MFMA C-regs; l comes from the ones-row (vdim 36) of vT.
__global__ void __launch_bounds__(256) k_attn(
    const ushort_t* __restrict__ q_bf, const ushort_t* __restrict__ k_bf,
    const ushort_t* __restrict__ vT, float* __restrict__ o_mv, float* __restrict__ o_s)
{
  __shared__ __align__(16) ushort_t plds[4][640];
  int bx = blockIdx.x;
  int bh = bx & 63, qb = bx >> 6;
  int b = bh >> 3, h = bh & 7;
  int t = threadIdx.x;
  int w = t >> 6, lane = t & 63;
  int quad = lane >> 4, col = lane & 15;
  int q16 = qb * 64 + w * 16;
  size_t hb = (size_t)bh * 1024;
  ushort_t* myp = &plds[w][0];

  // Q as B-operand: lane holds Q[q=col][d=quad*8+j]
  bf16x8 qfrag = *(const bf16x8*)(q_bf + (hb + q16 + col) * 32 + quad * 8);

  f32x4 ot0 = {0.f,0.f,0.f,0.f}, ot1 = {0.f,0.f,0.f,0.f}, ot2 = {0.f,0.f,0.f,0.f};

  const ushort_t* kbase = k_bf + hb * 32;
  const ushort_t* vbase = vT + (size_t)bh * 48 * 1024;

  for (int kt = 0; kt < 32; ++kt) {
    int kb = kt * 32;
    bf16x8 kf0 = *(const bf16x8*)(kbase + (size_t)(kb + col) * 32 + quad * 8);
    bf16x8 kf1 = *(const bf16x8*)(kbase + (size_t)(kb + 16 + col) * 32 + quad * 8);
    bf16x8 vf0 = *(const bf16x8*)(vbase + (size_t)(     col) * 1024 + kb + quad * 8);
    bf16x8 vf1 = *(const bf16x8*)(vbase + (size_t)(16 + col) * 1024 + kb + quad * 8);
    bf16x8 vf2 = *(const bf16x8*)(vbase + (size_t)(32 + col) * 1024 + kb + quad * 8);
    f32x4 zero = {0.f,0.f,0.f,0.f};
    // S^T[key=kb+tile*16+quad*4+r][q=col]
    f32x4 s0 = __builtin_amdgcn_mfma_f32_16x16x32_bf16(kf0, qfrag, zero, 0, 0, 0);
    f32x4 s1 = __builtin_amdgcn_mfma_f32_16x16x32_bf16(kf1, qfrag, zero, 0, 0, 0);

    // p = exp2(s); truncate to bf16 (bias cancels: l sums the same bf16 values)
    union { float f; uint_t u; } pa, pb, pc, pd;
    pa.f = exp2f(s0[0]); pb.f = exp2f(s0[1]);
    pc.f = exp2f(s0[2]); pd.f = exp2f(s0[3]);
    uint_t pk0 = __builtin_amdgcn_perm(pb.u, pa.u, 0x07060302u);
    uint_t pk1 = __builtin_amdgcn_perm(pd.u, pc.u, 0x07060302u);
    pa.f = exp2f(s1[0]); pb.f = exp2f(s1[1]);
    pc.f = exp2f(s1[2]); pd.f = exp2f(s1[3]);
    uint_t pk2 = __builtin_amdgcn_perm(pb.u, pa.u, 0x07060302u);
    uint_t pk3 = __builtin_amdgcn_perm(pd.u, pc.u, 0x07060302u);

    // P[q=col][local key]: keys quad*4+0..3 and 16+quad*4+0..3
    *(uint2*)(myp + col * 40 + quad * 4)      = make_uint2(pk0, pk1);
    *(uint2*)(myp + col * 40 + 16 + quad * 4) = make_uint2(pk2, pk3);
    __builtin_amdgcn_wave_barrier();
    // P^T as B-operand: lane holds P[q=col][key=quad*8+j]
    bf16x8 pfrag = *(const bf16x8*)(myp + col * 40 + quad * 8);
    __builtin_amdgcn_wave_barrier();
    ot0 = __builtin_amdgcn_mfma_f32_16x16x32_bf16(vf0, pfrag, ot0, 0, 0, 0);
    ot1 = __builtin_amdgcn_mfma_f32_16x16x32_bf16(vf1, pfrag, ot1, 0, 0, 0);
    ot2 = __builtin_amdgcn_mfma_f32_16x16x32_bf16(vf2, pfrag, ot2, 0, 0, 0);
  }

  // l = ones-row output: vdim 36 = tile2, m=4 -> quad 1, reg 0
  float lsum = __shfl(ot2[0], 16 + col, 64);
  float invl = 1.f / lsum;
  int tok = b * NN + q16 + col;
  float* op0 = o_mv + (size_t)tok * 256 + (2 * h) * 16 + quad * 4;
  op0[0] = ot0[0] * invl; op0[1] = ot0[1] * invl;
  op0[2] = ot0[2] * invl; op0[3] = ot0[3] * invl;
  float* op1 = o_mv + (size_t)tok * 256 + (2 * h + 1) * 16 + quad * 4;
  op1[0] = ot1[0] * invl; op1[1] = ot1[1] * invl;
  op1[2] = ot1[2] * invl; op1[3] = ot1[3] * invl;
  if (quad == 0) {
    float* osp = o_s + (size_t)tok * 32 + h * 4;
    osp[0] = ot2[0] * invl; osp[1] = ot2[1] * invl;
    osp[2] = ot2[2] * invl; osp[3] = ot2[3] * invl;
  }
}

// ---------------- attention out-proj + residual, 8-token tile ----------------
__global__ void __launch_bounds__(256) k_out_res(
    const float* __restrict__ o_mv, const float* __restrict__ o_s,
    const float* __restrict__ wmv, const float* __restrict__ wsm,
    const float* __restrict__ wms, const float* __restrict__ wss,
    float* __restrict__ mv, float* __restrict__ s)
{
  __shared__ float pool[4480];
  float* xo  = pool;          // [8][256]
  float* xso = pool + 2048;   // [8][32]
  float* yst = pool + 2304;   // [8][16] rows, stride 17

  int t = threadIdx.x;
  int tok0 = blockIdx.x * 8;
  int a = t & 15, og = t >> 4;
  int g = d_GRADE[a], pr = d_PAIR[a];

  float wg[16], wp[16];
  #pragma unroll
  for (int i = 0; i < 16; ++i) {
    wg[i] = wmv[og * 144 + i * 9 + g];
    wp[i] = wmv[og * 144 + i * 9 + 4 + g];
  }

  #pragma unroll
  for (int j = 0; j < 2; ++j)
    *(float4*)&xo[t * 4 + j * 1024] = *(const float4*)&o_mv[(size_t)tok0 * 256 + t * 4 + j * 1024];
  if (t < 64)
    *(float4*)&xso[t * 4] = *(const float4*)&o_s[(size_t)tok0 * 32 + t * 4];
  __syncthreads();

  for (int tk = 0; tk < 8; ++tk) {
    float y = 0.f;
    const float* xb = &xo[tk * 256];
    #pragma unroll
    for (int i = 0; i < 16; ++i) y += wg[i] * xb[i * 16 + a];
    if (pr >= 0) {
      #pragma unroll
      for (int i = 0; i < 16; ++i) y += wp[i] * xb[i * 16 + pr];
    }
    yst[(tk * 16 + og) * 17 + a] = y;
  }
  __syncthreads();

  if (t < 128) {
    int tk = t >> 4, o = t & 15;
    float add = 0.f;
    #pragma unroll
    for (int j = 0; j < 32; ++j) add += wsm[o * 32 + j] * xso[tk * 32 + j];
    yst[(tk * 16 + o) * 17 + 0] += add;
  }
  {
    int o32 = t & 31, tk = t >> 5;
    float ys = 0.f;
    #pragma unroll
    for (int j = 0; j < 32; ++j) ys += wss[o32 * 32 + j] * xso[tk * 32 + j];
    #pragma unroll
    for (int i = 0; i < 16; ++i) ys += wms[o32 * 16 + i] * xo[tk * 256 + i * 16];
    s[(size_t)(tok0 + tk) * 32 + o32] += ys;
  }
  __syncthreads();

  #pragma unroll
  for (int p = 0; p < 8; ++p) {
    int flat = p * 256 + t;
    int tk = flat >> 8, rem = flat & 255, o = rem >> 4, a2 = rem & 15;
    mv[(size_t)tok0 * 256 + flat] += yst[(tk * 16 + o) * 17 + a2];
  }
}

// ---------------- LN + geometric MLP + residual, 8-token tile ----------------
__global__ void __launch_bounds__(256) k_mlp_res(
    float* __restrict__ mv, float* __restrict__ s,
    const float* __restrict__ w1mv, const float* __restrict__ w1sm,
    const float* __restrict__ w1ms, const float* __restrict__ w1ss,
    const float* __restrict__ w2mv, const float* __restrict__ w2sm,
    const float* __restrict__ w2ms, const float* __restrict__ w2ss)
{
  __shared__ float pool[9600];
  float* xmv  = pool;           // [8][256]
  float* xs   = pool + 2048;    // [8][32]
  float* hst  = pool + 2304;    // [8][32] rows, stride 17  (aliased by y2st later)
  float* y2st = pool + 2304;    // [8][16] rows, stride 17  (alias of hst)
  float* hsst = pool + 6656;    // [8][64]
  float* gst  = pool + 7168;    // [8][16] rows, stride 17
  float* shst = pool + 9344;    // [8][32]

  int t = threadIdx.x;
  int tok0 = blockIdx.x * 8;
  int a = t & 15, og = t >> 4;
  int g = d_GRADE[a], pr = d_PAIR[a];

  // GP sign/index packing for output blade k=a
  unsigned long long jpack = 0; unsigned int spack = 0, skipm = 0;
  {
    int mk = d_I2M[a];
    for (int i = 0; i < 16; ++i) {
      int mi = d_I2M[i];
      int mj = mi ^ mk;
      if (mi & mj & 1) { skipm |= 1u << i; continue; }
      int j = d_M2I[mj];
      int sw = 0;
      for (int bb2 = 0; bb2 < 4; ++bb2)
        if (mj & (1 << bb2)) sw += __popc(((unsigned)mi) >> (bb2 + 1));
      jpack |= (unsigned long long)j << (4 * i);
      spack |= (unsigned)(sw & 1) << i;
    }
  }

  float wg1a[16], wp1a[16], wg1b[16], wp1b[16];
  #pragma unroll
  for (int i = 0; i < 16; ++i) {
    wg1a[i] = w1mv[(og)      * 144 + i * 9 + g];
    wg1b[i] = w1mv[(16 + og) * 144 + i * 9 + g];
    wp1a[i] = w1mv[(og)      * 144 + i * 9 + 4 + g];
    wp1b[i] = w1mv[(16 + og) * 144 + i * 9 + 4 + g];
  }

  #pragma unroll
  for (int j = 0; j < 2; ++j)
    *(float4*)&xmv[t * 4 + j * 1024] = *(const float4*)&mv[(size_t)tok0 * 256 + t * 4 + j * 1024];
  if (t < 64)
    *(float4*)&xs[t * 4] = *(const float4*)&s[(size_t)tok0 * 32 + t * 4];
  __syncthreads();

  if (t < 128) {
    int tk = t >> 4, ch = t & 15;
    float* xp = &xmv[tk * 256 + ch * 16];
    float4 v0 = *(float4*)&xp[0], v1 = *(float4*)&xp[4];
    float4 v2 = *(float4*)&xp[8], v3 = *(float4*)&xp[12];
    float ss = v0.x*v0.x + v0.z*v0.z + v0.w*v0.w + v1.x*v1.x
             + v2.x*v2.x + v2.y*v2.y + v2.z*v2.z + v3.z*v3.z;
    ss += __shfl_xor(ss, 1); ss += __shfl_xor(ss, 2);
    ss += __shfl_xor(ss, 4); ss += __shfl_xor(ss, 8);
    float inv = rsqrtf(ss / 16.f + 1e-6f);
    v0.x*=inv; v0.y*=inv; v0.z*=inv; v0.w*=inv;
    v1.x*=inv; v1.y*=inv; v1.z*=inv; v1.w*=inv;
    v2.x*=inv; v2.y*=inv; v2.z*=inv; v2.w*=inv;
    v3.x*=inv; v3.y*=inv; v3.z*=inv; v3.w*=inv;
    *(float4*)&xp[0] = v0; *(float4*)&xp[4] = v1;
    *(float4*)&xp[8] = v2; *(float4*)&xp[12] = v3;
    float s0 = xs[tk * 32 + ch * 2], s1 = xs[tk * 32 + ch * 2 + 1];
    float s2 = s0 * s0 + s1 * s1;
    s2 += __shfl_xor(s2, 1); s2 += __shfl_xor(s2, 2);
    s2 += __shfl_xor(s2, 4); s2 += __shfl_xor(s2, 8);
    float sinv = rsqrtf(s2 / 32.f + 1e-6f);
    xs[tk * 32 + ch * 2] = s0 * sinv;
    xs[tk * 32 + ch * 2 + 1] = s1 * sinv;
  }
  __syncthreads();

  // h1 = equi_linear1 (32 mv channels)
  for (int tk = 0; tk < 8; ++tk) {
    float y0 = 0.f, y1 = 0.f;
    const float* xb = &xmv[tk * 256];
    #pragma unroll
    for (int i = 0; i < 16; ++i) {
      float xa_ = xb[i * 16 + a];
      y0 += wg1a[i] * xa_; y1 += wg1b[i] * xa_;
    }
    if (pr >= 0) {
      #pragma unroll
      for (int i = 0; i < 16; ++i) {
        float xp_ = xb[i * 16 + pr];
        y0 += wp1a[i] * xp_; y1 += wp1b[i] * xp_;
      }
    }
    hst[(tk * 32 + og) * 17 + a] = y0;
    hst[(tk * 32 + 16 + og) * 17 + a] = y1;
  }
  // scalar h (64 per token)
  for (int u = t; u < 512; u += 256) {
    int tk = u >> 6, o64 = u & 63;
    float yy = 0.f;
    #pragma unroll
    for (int j = 0; j < 32; ++j) yy += w1ss[o64 * 32 + j] * xs[tk * 32 + j];
    #pragma unroll
    for (int i = 0; i < 16; ++i) yy += w1ms[o64 * 16 + i] * xmv[tk * 256 + i * 16];
    hsst[tk * 64 + o64] = yy;
  }
  __syncthreads();

  // w1sm into blade-0 column
  {
    int tk = t >> 5, o = t & 31;
    float add = 0.f;
    #pragma unroll
    for (int j = 0; j < 32; ++j) add += w1sm[o * 32 + j] * xs[tk * 32 + j];
    hst[(tk * 32 + o) * 17 + 0] += add;
  }
  __syncthreads();

  // geometric product + gate
  for (int tk = 0; tk < 8; ++tk) {
    const float* h1b = &hst[(tk * 32 + og) * 17];
    const float* h2b = &hst[(tk * 32 + 16 + og) * 17];
    float gacc = 0.f;
    #pragma unroll
    for (int i = 0; i < 16; ++i) {
      int j = (int)((jpack >> (4 * i)) & 15ull);
      float val = h1b[i] * h2b[j];
      float sv = ((spack >> i) & 1) ? -val : val;
      gacc += ((skipm >> i) & 1) ? 0.f : sv;
    }
    float gp0 = __shfl(gacc, (int)(t & 48), 64);
    gst[(tk * 16 + og) * 17 + a] = gacc * gelu_tanh(gp0);
  }
  // scalar gate
  {
    int tk = t >> 5, o32 = t & 31;
    shst[tk * 32 + o32] = hsst[tk * 64 + o32] * gelu_tanh(hsst[tk * 64 + 32 + o32]);
  }
  __syncthreads();

  // equi_linear2 (writes y2st, aliased onto hst region — hst is dead now)
  {
    float wg2[16], wp2[16];
    #pragma unroll
    for (int i = 0; i < 16; ++i) {
      wg2[i] = w2mv[og * 144 + i * 9 + g];
      wp2[i] = w2mv[og * 144 + i * 9 + 4 + g];
    }
    for (int tk = 0; tk < 8; ++tk) {
      float y = 0.f;
      #pragma unroll
      for (int i = 0; i < 16; ++i) y += wg2[i] * gst[(tk * 16 + i) * 17 + a];
      if (pr >= 0) {
        #pragma unroll
        for (int i = 0; i < 16; ++i) y += wp2[i] * gst[(tk * 16 + i) * 17 + pr];
      }
      y2st[(tk * 16 + og) * 17 + a] = y;
    }
  }
  __syncthreads();

  // w2sm into blade-0 column + s residual
  if (t < 128) {
    int tk = t >> 4, o = t & 15;
    float add = 0.f;
    #pragma unroll
    for (int j = 0; j < 32; ++j) add += w2sm[o * 32 + j] * shst[tk * 32 + j];
    y2st[(tk * 16 + o) * 17 + 0] += add;
  }
  {
    int tk = t >> 5, o32 = t & 31;
    float ys = 0.f;
    #pragma unroll
    for (int j = 0; j < 32; ++j) ys += w2ss[o32 * 32 + j] * shst[tk * 32 + j];
    #pragma unroll
    for (int i = 0; i < 16; ++i) ys += w2ms[o32 * 16 + i] * gst[(tk * 16 + i) * 17 + 0];
    s[(size_t)(tok0 + tk) * 32 + o32] += ys;
  }
  __syncthreads();

  // mv residual
  #pragma unroll
  for (int p = 0; p < 8; ++p) {
    int flat = p * 256 + t;
    int tk = flat >> 8, rem = flat & 255, o = rem >> 4, a2 = rem & 15;
    mv[(size_t)tok0 * 256 + flat] += y2st[(tk * 16 + o) * 17 + a2];
  }
}

// ---------------- final projection + mean ----------------
__global__ void __launch_bounds__(256) k_final(
    const float* __restrict__ mv, const float* __restrict__ s,
    const float* __restrict__ wout_mv, const float* __restrict__ wout_sm,
    float* __restrict__ out)
{
  __shared__ float red[256];
  int b = blockIdx.x, t = threadIdx.x;
  float part = 0.f;
  for (int n = t; n < NN; n += 256) {
    const float* mvp = mv + ((size_t)(b * NN + n) * 16) * 16;
    const float* sp = s + (size_t)(b * NN + n) * 32;
    float acc = 0.f;
    #pragma unroll
    for (int i = 0; i < 16; ++i) acc += wout_mv[i * 9] * mvp[i * 16];
    #pragma unroll
    for (int j = 0; j < 32; ++j) acc += wout_sm[j] * sp[j];
    part += acc;
  }
  red[t] = part;
  __syncthreads();
  for (int w = 128; w > 0; w >>= 1) { if (t < w) red[t] += red[t + w]; __syncthreads(); }
  if (t == 0) out[b] = red[0] / (float)NN;
}

extern "C" void kernel_launch(void* const* d_in, const int* in_sizes, int n_in,
                              void* d_out, int out_size, void* d_ws, size_t ws_size,
                              hipStream_t stream) {
  const float* inputs    = (const float*)d_in[0];
  const float* win_mv    = (const float*)d_in[1];
  const float* win_ms    = (const float*)d_in[2];
  const float* win_bs    = (const float*)d_in[3];
  const float* a_qkv_wmv = (const float*)d_in[4];
  const float* a_qkv_wsm = (const float*)d_in[5];
  const float* a_qkv_wms = (const float*)d_in[6];
  const float* a_qkv_wss = (const float*)d_in[7];
  const float* a_out_wmv = (const float*)d_in[8];
  const float* a_out_wsm = (const float*)d_in[9];
  const float* a_out_wms = (const float*)d_in[10];
  const float* a_out_wss = (const float*)d_in[11];
  const float* m1_wmv    = (const float*)d_in[12];
  const float* m1_wsm    = (const float*)d_in[13];
  const float* m1_wms    = (const float*)d_in[14];
  const float* m1_wss    = (const float*)d_in[15];
  const float* m2_wmv    = (const float*)d_in[16];
  const float* m2_wsm    = (const float*)d_in[17];
  const float* m2_wms    = (const float*)d_in[18];
  const float* m2_wss    = (const float*)d_in[19];
  const float* wout_mv   = (const float*)d_in[20];
  const float* wout_sm   = (const float*)d_in[21];
  float* out = (float*)d_out;

  float* ws = (float*)d_ws;
  float* mv   = ws;                  // 8*1024*256 = 2097152 f
  float* s    = mv + 2097152;        // 262144 f
  float* o_mv = s + 262144;          // 2097152 f
  float* o_s  = o_mv + 2097152;      // 262144 f
  ushort_t* q_bf = (ushort_t*)(o_s + 262144);  // 64*1024*32 = 2097152 bf16
  ushort_t* k_bf = q_bf + 2097152;             // 2097152 bf16
  ushort_t* vT   = k_bf + 2097152;             // 64*48*1024 = 3145728 bf16

  int ntok = BB * NN;
  int ntile = ntok / 8;  // 1024
  k_embed<<<ntok, 256, 0, stream>>>(inputs, win_mv, win_ms, win_bs, mv, s);

  for (int l = 0; l < LLAYERS; ++l) {
    k_ln_qkv<<<ntile, 256, 0, stream>>>(mv, s,
        a_qkv_wmv + (size_t)l * 48 * 16 * 9, a_qkv_wsm + (size_t)l * 48 * 32,
        a_qkv_wms + (size_t)l * 96 * 16,     a_qkv_wss + (size_t)l * 96 * 32,
        q_bf, k_bf, vT);
    k_attn<<<64 * 16, 256, 0, stream>>>(q_bf, k_bf, vT, o_mv, o_s);
    k_out_res<<<ntile, 256, 0, stream>>>(o_mv, o_s,
        a_out_wmv + (size_t)l * 16 * 16 * 9, a_out_wsm + (size_t)l * 16 * 32,
        a_out_wms + (size_t)l * 32 * 16,     a_out_wss + (size_t)l * 32 * 32,
        mv, s);
    k_mlp_res<<<ntile, 256, 0, stream>>>(mv, s,
        m1_wmv + (size_t)l * 32 * 16 * 9, m1_wsm + (size_t)l * 32 * 32,
        m1_wms + (size_t)l * 64 * 16,     m1_wss + (size_t)l * 64 * 32,
        m2_wmv + (size_t)l * 16 * 16 * 9, m2_wsm + (size_t)l * 16 * 32,
        m2_wms + (size_t)l * 32 * 16,     m2_wss + (size_t)l * 32 * 32);
  }

  k_final<<<BB, 256, 0, stream>>>(mv, s, wout_mv, wout_sm, out);

  (void)in_sizes; (void)n_in; (void)out_size; (void)ws_size;
}

// Round 6
// 1285.761 us; speedup vs baseline: 1.0154x; 1.0154x over previous
//
#include <hip/hip_runtime.h>
#include <math.h>

#define BB 8
#define NN 1024
#define LLAYERS 8

typedef unsigned short ushort_t;
typedef unsigned int uint_t;
using bf16x8 = __attribute__((ext_vector_type(8))) short;
using f32x4  = __attribute__((ext_vector_type(4))) float;

__constant__ int d_GRADE[16] = {0,1,1,1,1,2,2,2,2,2,2,3,3,3,3,4};
__constant__ int d_PAIR[16]  = {-1,0,-1,-1,-1,2,3,4,-1,-1,-1,8,9,10,-1,14};
__constant__ int d_IB[8] = {0,2,3,4,8,9,10,14};
__constant__ int d_I2M[16] = {0,1,2,4,8,3,5,9,6,10,12,7,11,13,14,15};
__constant__ int d_M2I[16] = {0,1,2,5,3,6,8,11,4,7,9,12,10,13,14,15};

#define QSCALE (0.22360679774997896f * 1.4426950408889634f)

// gelu(x)=0.5x(1+tanh(y)) = x/(1+exp(-2y)), y=0.79788456(x+0.044715x^3)
__device__ __forceinline__ float gelu_tanh(float x) {
  float y = 0.7978845608028654f * (x + 0.044715f * x * x * x);
  float e2 = __builtin_amdgcn_exp2f(y * -2.8853900817779268f);
  return x * __builtin_amdgcn_rcpf(1.0f + e2);
}

__device__ __forceinline__ ushort_t f2b(float f) {
  union { float f; unsigned int u; } x;
  x.f = f;
  unsigned int r = x.u + 0x7fffu + ((x.u >> 16) & 1u);  // RNE
  return (ushort_t)(r >> 16);
}

// ---------------- embed ----------------
__global__ void __launch_bounds__(256) k_embed(
    const float* __restrict__ inp, const float* __restrict__ win_mv,
    const float* __restrict__ win_ms, const float* __restrict__ win_bs,
    float* __restrict__ mv, float* __restrict__ s)
{
  int tok = blockIdx.x, t = threadIdx.x;
  float x = inp[tok * 3 + 0];
  float y = inp[tok * 3 + 1];
  float z = inp[tok * 3 + 2];
  int o = t >> 4, aa = t & 15;
  float ma = (aa == 14) ? 1.f : (aa == 13) ? -x : (aa == 12) ? y : (aa == 11) ? -z : 0.f;
  int g = d_GRADE[aa];
  float val = win_mv[o * 9 + g] * ma;
  int pr = d_PAIR[aa];
  if (pr >= 0) {
    float mp = (pr == 14) ? 1.f : 0.f;
    val += win_mv[o * 9 + 4 + g] * mp;
  }
  mv[(size_t)tok * 256 + t] = val;
  if (t < 32) s[(size_t)tok * 32 + t] = win_bs[t];
  (void)win_ms;
}

// ---------------- LN + QKV projection, 8-token tile ----------------
__global__ void __launch_bounds__(256) k_ln_qkv(
    const float* __restrict__ mv, const float* __restrict__ s,
    const float* __restrict__ wmv, const float* __restrict__ wsm,
    const float* __restrict__ wms, const float* __restrict__ wss,
    ushort_t* __restrict__ q_bf, ushort_t* __restrict__ k_bf, ushort_t* __restrict__ vT)
{
  __shared__ float pool[9600];
  float* xmv = pool;           // [8][256]
  float* xs  = pool + 2048;    // [8][32]
  float* yst = pool + 2304;    // [8][48] rows, stride 17
  float* sst = pool + 8832;    // [8][96]

  int t = threadIdx.x;
  int tok0 = blockIdx.x * 8;
  int b = tok0 >> 10, n0 = tok0 & 1023;
  int a = t & 15, og = t >> 4;
  int g = d_GRADE[a], pr = d_PAIR[a];

  float wgq[16], wpq[16], wgk[16], wpk[16], wgv[16], wpv[16];
  #pragma unroll
  for (int i = 0; i < 16; ++i) {
    wgq[i] = wmv[(og)      * 144 + i * 9 + g];
    wgk[i] = wmv[(16 + og) * 144 + i * 9 + g];
    wgv[i] = wmv[(32 + og) * 144 + i * 9 + g];
    wpq[i] = wmv[(og)      * 144 + i * 9 + 4 + g];
    wpk[i] = wmv[(16 + og) * 144 + i * 9 + 4 + g];
    wpv[i] = wmv[(32 + og) * 144 + i * 9 + 4 + g];
  }

  #pragma unroll
  for (int j = 0; j < 2; ++j)
    *(float4*)&xmv[t * 4 + j * 1024] = *(const float4*)&mv[(size_t)tok0 * 256 + t * 4 + j * 1024];
  if (t < 64)
    *(float4*)&xs[t * 4] = *(const float4*)&s[(size_t)tok0 * 32 + t * 4];
  __syncthreads();

  if (t < 128) {
    int tk = t >> 4, ch = t & 15;
    float* xp = &xmv[tk * 256 + ch * 16];
    float4 v0 = *(float4*)&xp[0], v1 = *(float4*)&xp[4];
    float4 v2 = *(float4*)&xp[8], v3 = *(float4*)&xp[12];
    float ss = v0.x*v0.x + v0.z*v0.z + v0.w*v0.w + v1.x*v1.x
             + v2.x*v2.x + v2.y*v2.y + v2.z*v2.z + v3.z*v3.z;
    ss += __shfl_xor(ss, 1); ss += __shfl_xor(ss, 2);
    ss += __shfl_xor(ss, 4); ss += __shfl_xor(ss, 8);
    float inv = rsqrtf(ss / 16.f + 1e-6f);
    v0.x*=inv; v0.y*=inv; v0.z*=inv; v0.w*=inv;
    v1.x*=inv; v1.y*=inv; v1.z*=inv; v1.w*=inv;
    v2.x*=inv; v2.y*=inv; v2.z*=inv; v2.w*=inv;
    v3.x*=inv; v3.y*=inv; v3.z*=inv; v3.w*=inv;
    *(float4*)&xp[0] = v0; *(float4*)&xp[4] = v1;
    *(float4*)&xp[8] = v2; *(float4*)&xp[12] = v3;
    float s0 = xs[tk * 32 + ch * 2], s1 = xs[tk * 32 + ch * 2 + 1];
    float s2 = s0 * s0 + s1 * s1;
    s2 += __shfl_xor(s2, 1); s2 += __shfl_xor(s2, 2);
    s2 += __shfl_xor(s2, 4); s2 += __shfl_xor(s2, 8);
    float sinv = rsqrtf(s2 / 32.f + 1e-6f);
    xs[tk * 32 + ch * 2] = s0 * sinv;
    xs[tk * 32 + ch * 2 + 1] = s1 * sinv;
  }
  __syncthreads();

  for (int tk = 0; tk < 8; ++tk) {
    float y0 = 0.f, y1 = 0.f, y2 = 0.f;
    const float* xb = &xmv[tk * 256];
    #pragma unroll
    for (int i = 0; i < 16; ++i) {
      float xa_ = xb[i * 16 + a];
      y0 += wgq[i] * xa_; y1 += wgk[i] * xa_; y2 += wgv[i] * xa_;
    }
    if (pr >= 0) {
      #pragma unroll
      for (int i = 0; i < 16; ++i) {
        float xp_ = xb[i * 16 + pr];
        y0 += wpq[i] * xp_; y1 += wpk[i] * xp_; y2 += wpv[i] * xp_;
      }
    }
    yst[(tk * 48 + og) * 17 + a] = y0;
    yst[(tk * 48 + 16 + og) * 17 + a] = y1;
    yst[(tk * 48 + 32 + og) * 17 + a] = y2;
  }
  __syncthreads();

  for (int u = t; u < 384; u += 256) {
    int tk = u / 48, o = u % 48;
    float add = 0.f;
    #pragma unroll
    for (int j = 0; j < 32; ++j) add += wsm[o * 32 + j] * xs[tk * 32 + j];
    yst[(tk * 48 + o) * 17 + 0] += add;
  }
  for (int u = t; u < 768; u += 256) {
    int tk = u / 96, o96 = u % 96;
    float yy = 0.f;
    #pragma unroll
    for (int j = 0; j < 32; ++j) yy += wss[o96 * 32 + j] * xs[tk * 32 + j];
    #pragma unroll
    for (int i = 0; i < 16; ++i) yy += wms[o96 * 16 + i] * xmv[tk * 256 + i * 16];
    sst[tk * 96 + o96] = yy;
  }
  __syncthreads();

  if (t < 128) {
    int isK = t >> 6;
    int r = t & 63;
    int tk = r >> 3, h = r & 7;
    float scale = isK ? 1.f : QSCALE;
    const float* base = &yst[(tk * 48 + isK * 16) * 17];
    ushort_t tmp[32];
    #pragma unroll
    for (int j = 0; j < 8; ++j) {
      int blade = d_IB[j];
      tmp[j]     = f2b(base[(2 * h)     * 17 + blade] * scale);
      tmp[8 + j] = f2b(base[(2 * h + 1) * 17 + blade] * scale);
    }
    #pragma unroll
    for (int d = 0; d < 4; ++d)
      tmp[16 + d] = f2b(sst[tk * 96 + isK * 32 + h * 4 + d] * scale);
    #pragma unroll
    for (int j2 = 20; j2 < 32; ++j2) tmp[j2] = 0;
    uint_t out[16];
    #pragma unroll
    for (int j3 = 0; j3 < 16; ++j3)
      out[j3] = (uint_t)tmp[2 * j3] | ((uint_t)tmp[2 * j3 + 1] << 16);
    ushort_t* dst = (isK ? k_bf : q_bf) + ((size_t)(b * 8 + h) * 1024 + n0 + tk) * 32;
    *(uint4*)(dst +  0) = make_uint4(out[0],  out[1],  out[2],  out[3]);
    *(uint4*)(dst +  8) = make_uint4(out[4],  out[5],  out[6],  out[7]);
    *(uint4*)(dst + 16) = make_uint4(out[8],  out[9],  out[10], out[11]);
    *(uint4*)(dst + 24) = make_uint4(out[12], out[13], out[14], out[15]);
  }
  {
    int h = t >> 5, dim = t & 31;
    int ch = 2 * h + (dim >> 4), blade = dim & 15;
    uint_t ov[4];
    #pragma unroll
    for (int tk = 0; tk < 8; ++tk) {
      ushort_t bv = f2b(yst[(tk * 48 + 32 + ch) * 17 + blade]);
      if (tk & 1) ov[tk >> 1] |= ((uint_t)bv) << 16; else ov[tk >> 1] = bv;
    }
    ushort_t* dst = vT + ((size_t)(b * 8 + h) * 48 + dim) * 1024 + n0;
    *(uint4*)dst = make_uint4(ov[0], ov[1], ov[2], ov[3]);
  }
  if (t < 32) {
    int h = t >> 2, d = t & 3;
    uint_t ov[4];
    #pragma unroll
    for (int tk = 0; tk < 8; ++tk) {
      ushort_t bv = f2b(sst[tk * 96 + 64 + h * 4 + d]);
      if (tk & 1) ov[tk >> 1] |= ((uint_t)bv) << 16; else ov[tk >> 1] = bv;
    }
    ushort_t* dst = vT + ((size_t)(b * 8 + h) * 48 + 32 + d) * 1024 + n0;
    *(uint4*)dst = make_uint4(ov[0], ov[1], ov[2], ov[3]);
  }
  if (t < 8) {
    ushort_t* dst = vT + ((size_t)(b * 8 + t) * 48 + 36) * 1024 + n0;
    *(uint4*)dst = make_uint4(0x3F803F80u, 0x3F803F80u, 0x3F803F80u, 0x3F803F80u);
  }
}

// ---------------- attention: bf16 MFMA, no-max softmax, key-split x2, 64-key body ----
#define OPART_STRIDE 2359296   // floats between A and B partial o_mv/o_s blocks
#define LPART_STRIDE 65536
__global__ void __launch_bounds__(256) k_attn(
    const ushort_t* __restrict__ q_bf, const ushort_t* __restrict__ k_bf,
    const ushort_t* __restrict__ vT, float* __restrict__ o_mvA, float* __restrict__ lA)
{
  __shared__ __align__(16) ushort_t plds[4][1280];
  int bx = blockIdx.x;
  int bh = bx & 63, qg = bx >> 6;
  int qb = qg & 15, kg = qg >> 4;
  int b = bh >> 3, h = bh & 7;
  int t = threadIdx.x;
  int w = t >> 6, lane = t & 63;
  int quad = lane >> 4, col = lane & 15;
  int q16 = qb * 64 + w * 16;
  size_t hb = (size_t)bh * 1024;
  ushort_t* myp = &plds[w][0];

  float* o_mvp = o_mvA + (size_t)kg * OPART_STRIDE;
  float* o_sp  = o_mvp + 2097152;
  float* l_p   = lA + (size_t)kg * LPART_STRIDE;

  bf16x8 qfrag = *(const bf16x8*)(q_bf + (hb + q16 + col) * 32 + quad * 8);

  f32x4 ot0 = {0.f,0.f,0.f,0.f}, ot1 = {0.f,0.f,0.f,0.f}, ot2 = {0.f,0.f,0.f,0.f};

  const ushort_t* kbase = k_bf + hb * 32;
  const ushort_t* vbase = vT + (size_t)bh * 48 * 1024;
  int k0 = kg * 512;

  for (int kt = 0; kt < 8; ++kt) {
    int kb = k0 + kt * 64;
    bf16x8 ka0 = *(const bf16x8*)(kbase + (size_t)(kb +      col) * 32 + quad * 8);
    bf16x8 ka1 = *(const bf16x8*)(kbase + (size_t)(kb + 16 + col) * 32 + quad * 8);
    bf16x8 kb0 = *(const bf16x8*)(kbase + (size_t)(kb + 32 + col) * 32 + quad * 8);
    bf16x8 kb1 = *(const bf16x8*)(kbase + (size_t)(kb + 48 + col) * 32 + quad * 8);
    bf16x8 va0 = *(const bf16x8*)(vbase + (size_t)(     col) * 1024 + kb + quad * 8);
    bf16x8 va1 = *(const bf16x8*)(vbase + (size_t)(16 + col) * 1024 + kb + quad * 8);
    bf16x8 va2 = *(const bf16x8*)(vbase + (size_t)(32 + col) * 1024 + kb + quad * 8);
    bf16x8 vb0 = *(const bf16x8*)(vbase + (size_t)(     col) * 1024 + kb + 32 + quad * 8);
    bf16x8 vb1 = *(const bf16x8*)(vbase + (size_t)(16 + col) * 1024 + kb + 32 + quad * 8);
    bf16x8 vb2 = *(const bf16x8*)(vbase + (size_t)(32 + col) * 1024 + kb + 32 + quad * 8);
    f32x4 zero = {0.f,0.f,0.f,0.f};
    f32x4 sa0 = __builtin_amdgcn_mfma_f32_16x16x32_bf16(ka0, qfrag, zero, 0, 0, 0);
    f32x4 sa1 = __builtin_amdgcn_mfma_f32_16x16x32_bf16(ka1, qfrag, zero, 0, 0, 0);
    f32x4 sb0 = __builtin_amdgcn_mfma_f32_16x16x32_bf16(kb0, qfrag, zero, 0, 0, 0);
    f32x4 sb1 = __builtin_amdgcn_mfma_f32_16x16x32_bf16(kb1, qfrag, zero, 0, 0, 0);

    union { float f; uint_t u; } e0, e1, e2, e3;
    e0.f = __builtin_amdgcn_exp2f(sa0[0]); e1.f = __builtin_amdgcn_exp2f(sa0[1]);
    e2.f = __builtin_amdgcn_exp2f(sa0[2]); e3.f = __builtin_amdgcn_exp2f(sa0[3]);
    uint_t a0 = __builtin_amdgcn_perm(e1.u, e0.u, 0x07060302u);
    uint_t a1 = __builtin_amdgcn_perm(e3.u, e2.u, 0x07060302u);
    e0.f = __builtin_amdgcn_exp2f(sa1[0]); e1.f = __builtin_amdgcn_exp2f(sa1[1]);
    e2.f = __builtin_amdgcn_exp2f(sa1[2]); e3.f = __builtin_amdgcn_exp2f(sa1[3]);
    uint_t a2 = __builtin_amdgcn_perm(e1.u, e0.u, 0x07060302u);
    uint_t a3 = __builtin_amdgcn_perm(e3.u, e2.u, 0x07060302u);
    e0.f = __builtin_amdgcn_exp2f(sb0[0]); e1.f = __builtin_amdgcn_exp2f(sb0[1]);
    e2.f = __builtin_amdgcn_exp2f(sb0[2]); e3.f = __builtin_amdgcn_exp2f(sb0[3]);
    uint_t b0 = __builtin_amdgcn_perm(e1.u, e0.u, 0x07060302u);
    uint_t b1 = __builtin_amdgcn_perm(e3.u, e2.u, 0x07060302u);
    e0.f = __builtin_amdgcn_exp2f(sb1[0]); e1.f = __builtin_amdgcn_exp2f(sb1[1]);
    e2.f = __builtin_amdgcn_exp2f(sb1[2]); e3.f = __builtin_amdgcn_exp2f(sb1[3]);
    uint_t b2 = __builtin_amdgcn_perm(e1.u, e0.u, 0x07060302u);
    uint_t b3 = __builtin_amdgcn_perm(e3.u, e2.u, 0x07060302u);

    *(uint2*)(myp + col * 40 + quad * 4)            = make_uint2(a0, a1);
    *(uint2*)(myp + col * 40 + 16 + quad * 4)       = make_uint2(a2, a3);
    *(uint2*)(myp + 640 + col * 40 + quad * 4)      = make_uint2(b0, b1);
    *(uint2*)(myp + 640 + col * 40 + 16 + quad * 4) = make_uint2(b2, b3);
    __builtin_amdgcn_wave_barrier();
    bf16x8 pfa = *(const bf16x8*)(myp + col * 40 + quad * 8);
    bf16x8 pfb = *(const bf16x8*)(myp + 640 + col * 40 + quad * 8);
    __builtin_amdgcn_wave_barrier();
    ot0 = __builtin_amdgcn_mfma_f32_16x16x32_bf16(va0, pfa, ot0, 0, 0, 0);
    ot1 = __builtin_amdgcn_mfma_f32_16x16x32_bf16(va1, pfa, ot1, 0, 0, 0);
    ot2 = __builtin_amdgcn_mfma_f32_16x16x32_bf16(va2, pfa, ot2, 0, 0, 0);
    ot0 = __builtin_amdgcn_mfma_f32_16x16x32_bf16(vb0, pfb, ot0, 0, 0, 0);
    ot1 = __builtin_amdgcn_mfma_f32_16x16x32_bf16(vb1, pfb, ot1, 0, 0, 0);
    ot2 = __builtin_amdgcn_mfma_f32_16x16x32_bf16(vb2, pfb, ot2, 0, 0, 0);
  }

  int tok = b * NN + q16 + col;
  float* op0 = o_mvp + (size_t)tok * 256 + (2 * h) * 16 + quad * 4;
  op0[0] = ot0[0]; op0[1] = ot0[1]; op0[2] = ot0[2]; op0[3] = ot0[3];
  float* op1 = o_mvp + (size_t)tok * 256 + (2 * h + 1) * 16 + quad * 4;
  op1[0] = ot1[0]; op1[1] = ot1[1]; op1[2] = ot1[2]; op1[3] = ot1[3];
  if (quad == 0) {
    float* osp = o_sp + (size_t)tok * 32 + h * 4;
    osp[0] = ot2[0]; osp[1] = ot2[1]; osp[2] = ot2[2]; osp[3] = ot2[3];
  }
  if (quad == 1) l_p[hb + q16 + col] = ot2[0];
}

// ---------------- attention combine + out-proj + residual, 8-token tile ----------------
__global__ void __launch_bounds__(256) k_out_res(
    const float* __restrict__ o_mvA, const float* __restrict__ lA,
    const float* __restrict__ wmv, const float* __restrict__ wsm,
    const float* __restrict__ wms, const float* __restrict__ wss,
    float* __restrict__ mv, float* __restrict__ s)
{
  __shared__ float pool[4544];
  float* xo    = pool;          // [8][256]
  float* xso   = pool + 2048;   // [8][32]
  float* yst   = pool + 2304;   // [8][16] rows, stride 17
  float* invls = pool + 4480;   // [8][8]

  const float* o_sA  = o_mvA + 2097152;
  const float* o_mvB = o_mvA + OPART_STRIDE;
  const float* o_sB  = o_mvB + 2097152;
  const float* lB    = lA + LPART_STRIDE;

  int t = threadIdx.x;
  int tok0 = blockIdx.x * 8;
  int b8 = (tok0 >> 10) * 8, n0 = tok0 & 1023;
  int a = t & 15, og = t >> 4;
  int g = d_GRADE[a], pr = d_PAIR[a];

  float wg[16], wp[16];
  #pragma unroll
  for (int i = 0; i < 16; ++i) {
    wg[i] = wmv[og * 144 + i * 9 + g];
    wp[i] = wmv[og * 144 + i * 9 + 4 + g];
  }

  float4 ra[2], rc[2];
  #pragma unroll
  for (int j = 0; j < 2; ++j) {
    ra[j] = *(const float4*)&o_mvA[(size_t)tok0 * 256 + t * 4 + j * 1024];
    rc[j] = *(const float4*)&o_mvB[(size_t)tok0 * 256 + t * 4 + j * 1024];
  }
  float4 sa4 = {0,0,0,0}, sc4 = {0,0,0,0};
  if (t < 64) {
    int tk = t >> 3, h = t & 7;
    sa4 = *(const float4*)&o_sA[(size_t)(tok0 + tk) * 32 + h * 4];
    sc4 = *(const float4*)&o_sB[(size_t)(tok0 + tk) * 32 + h * 4];
    float la = lA[(size_t)(b8 + h) * 1024 + n0 + tk];
    float lb = lB[(size_t)(b8 + h) * 1024 + n0 + tk];
    invls[t] = 1.f / (la + lb);
  }
  __syncthreads();

  #pragma unroll
  for (int j = 0; j < 2; ++j) {
    int idx = t * 4 + j * 1024;
    int tk = idx >> 8, o = (idx >> 4) & 15;
    float il = invls[tk * 8 + (o >> 1)];
    xo[idx + 0] = (ra[j].x + rc[j].x) * il;
    xo[idx + 1] = (ra[j].y + rc[j].y) * il;
    xo[idx + 2] = (ra[j].z + rc[j].z) * il;
    xo[idx + 3] = (ra[j].w + rc[j].w) * il;
  }
  if (t < 64) {
    int tk = t >> 3, h = t & 7;
    float il = invls[t];
    xso[tk * 32 + h * 4 + 0] = (sa4.x + sc4.x) * il;
    xso[tk * 32 + h * 4 + 1] = (sa4.y + sc4.y) * il;
    xso[tk * 32 + h * 4 + 2] = (sa4.z + sc4.z) * il;
    xso[tk * 32 + h * 4 + 3] = (sa4.w + sc4.w) * il;
  }
  __syncthreads();

  for (int tk = 0; tk < 8; ++tk) {
    float y = 0.f;
    const float* xb = &xo[tk * 256];
    #pragma unroll
    for (int i = 0; i < 16; ++i) y += wg[i] * xb[i * 16 + a];
    if (pr >= 0) {
      #pragma unroll
      for (int i = 0; i < 16; ++i) y += wp[i] * xb[i * 16 + pr];
    }
    yst[(tk * 16 + og) * 17 + a] = y;
  }
  __syncthreads();

  if (t < 128) {
    int tk = t >> 4, o = t & 15;
    float add = 0.f;
    #pragma unroll
    for (int j = 0; j < 32; ++j) add += wsm[o * 32 + j] * xso[tk * 32 + j];
    yst[(tk * 16 + o) * 17 + 0] += add;
  }
  {
    int o32 = t & 31, tk = t >> 5;
    float ys = 0.f;
    #pragma unroll
    for (int j = 0; j < 32; ++j) ys += wss[o32 * 32 + j] * xso[tk * 32 + j];
    #pragma unroll
    for (int i = 0; i < 16; ++i) ys += wms[o32 * 16 + i] * xo[tk * 256 + i * 16];
    s[(size_t)(tok0 + tk) * 32 + o32] += ys;
  }
  __syncthreads();

  #pragma unroll
  for (int p = 0; p < 8; ++p) {
    int flat = p * 256 + t;
    int tk = flat >> 8, rem = flat & 255, o = rem >> 4, a2 = rem & 15;
    mv[(size_t)tok0 * 256 + flat] += yst[(tk * 16 + o) * 17 + a2];
  }
}

// ---------------- LN + geometric MLP + residual, 8-token tile ----------------
__global__ void __launch_bounds__(256) k_mlp_res(
    float* __restrict__ mv, float* __restrict__ s,
    const float* __restrict__ w1mv, const float* __restrict__ w1sm,
    const float* __restrict__ w1ms, const float* __restrict__ w1ss,
    const float* __restrict__ w2mv, const float* __restrict__ w2sm,
    const float* __restrict__ w2ms, const float* __restrict__ w2ss)
{
  __shared__ float pool[9600];
  float* xmv  = pool;           // [8][256]
  float* xs   = pool + 2048;    // [8][32]
  float* hst  = pool + 2304;    // [8][32] rows, stride 17
  float* y2st = pool + 2304;    // alias of hst (dead when reused)
  float* hsst = pool + 6656;    // [8][64]
  float* gst  = pool + 7168;    // [8][16] rows, stride 17
  float* shst = pool + 9344;    // [8][32]

  int t = threadIdx.x;
  int tok0 = blockIdx.x * 8;
  int a = t & 15, og = t >> 4;
  int g = d_GRADE[a], pr = d_PAIR[a];

  unsigned long long jpack = 0; unsigned int spack = 0, skipm = 0;
  {
    int mk = d_I2M[a];
    for (int i = 0; i < 16; ++i) {
      int mi = d_I2M[i];
      int mj = mi ^ mk;
      if (mi & mj & 1) { skipm |= 1u << i; continue; }
      int j = d_M2I[mj];
      int sw = 0;
      for (int bb2 = 0; bb2 < 4; ++bb2)
        if (mj & (1 << bb2)) sw += __popc(((unsigned)mi) >> (bb2 + 1));
      jpack |= (unsigned long long)j << (4 * i);
      spack |= (unsigned)(sw & 1) << i;
    }
  }

  float wg1a[16], wp1a[16], wg1b[16], wp1b[16];
  #pragma unroll
  for (int i = 0; i < 16; ++i) {
    wg1a[i] = w1mv[(og)      * 144 + i * 9 + g];
    wg1b[i] = w1mv[(16 + og) * 144 + i * 9 + g];
    wp1a[i] = w1mv[(og)      * 144 + i * 9 + 4 + g];
    wp1b[i] = w1mv[(16 + og) * 144 + i * 9 + 4 + g];
  }

  #pragma unroll
  for (int j = 0; j < 2; ++j)
    *(float4*)&xmv[t * 4 + j * 1024] = *(const float4*)&mv[(size_t)tok0 * 256 + t * 4 + j * 1024];
  if (t < 64)
    *(float4*)&xs[t * 4] = *(const float4*)&s[(size_t)tok0 * 32 + t * 4];
  __syncthreads();

  if (t < 128) {
    int tk = t >> 4, ch = t & 15;
    float* xp = &xmv[tk * 256 + ch * 16];
    float4 v0 = *(float4*)&xp[0], v1 = *(float4*)&xp[4];
    float4 v2 = *(float4*)&xp[8], v3 = *(float4*)&xp[12];
    float ss = v0.x*v0.x + v0.z*v0.z + v0.w*v0.w + v1.x*v1.x
             + v2.x*v2.x + v2.y*v2.y + v2.z*v2.z + v3.z*v3.z;
    ss += __shfl_xor(ss, 1); ss += __shfl_xor(ss, 2);
    ss += __shfl_xor(ss, 4); ss += __shfl_xor(ss, 8);
    float inv = rsqrtf(ss / 16.f + 1e-6f);
    v0.x*=inv; v0.y*=inv; v0.z*=inv; v0.w*=inv;
    v1.x*=inv; v1.y*=inv; v1.z*=inv; v1.w*=inv;
    v2.x*=inv; v2.y*=inv; v2.z*=inv; v2.w*=inv;
    v3.x*=inv; v3.y*=inv; v3.z*=inv; v3.w*=inv;
    *(float4*)&xp[0] = v0; *(float4*)&xp[4] = v1;
    *(float4*)&xp[8] = v2; *(float4*)&xp[12] = v3;
    float s0 = xs[tk * 32 + ch * 2], s1 = xs[tk * 32 + ch * 2 + 1];
    float s2 = s0 * s0 + s1 * s1;
    s2 += __shfl_xor(s2, 1); s2 += __shfl_xor(s2, 2);
    s2 += __shfl_xor(s2, 4); s2 += __shfl_xor(s2, 8);
    float sinv = rsqrtf(s2 / 32.f + 1e-6f);
    xs[tk * 32 + ch * 2] = s0 * sinv;
    xs[tk * 32 + ch * 2 + 1] = s1 * sinv;
  }
  __syncthreads();

  for (int tk = 0; tk < 8; ++tk) {
    float y0 = 0.f, y1 = 0.f;
    const float* xb = &xmv[tk * 256];
    #pragma unroll
    for (int i = 0; i < 16; ++i) {
      float xa_ = xb[i * 16 + a];
      y0 += wg1a[i] * xa_; y1 += wg1b[i] * xa_;
    }
    if (pr >= 0) {
      #pragma unroll
      for (int i = 0; i < 16; ++i) {
        float xp_ = xb[i * 16 + pr];
        y0 += wp1a[i] * xp_; y1 += wp1b[i] * xp_;
      }
    }
    hst[(tk * 32 + og) * 17 + a] = y0;
    hst[(tk * 32 + 16 + og) * 17 + a] = y1;
  }
  for (int u = t; u < 512; u += 256) {
    int tk = u >> 6, o64 = u & 63;
    float yy = 0.f;
    #pragma unroll
    for (int j = 0; j < 32; ++j) yy += w1ss[o64 * 32 + j] * xs[tk * 32 + j];
    #pragma unroll
    for (int i = 0; i < 16; ++i) yy += w1ms[o64 * 16 + i] * xmv[tk * 256 + i * 16];
    hsst[tk * 64 + o64] = yy;
  }
  __syncthreads();

  {
    int tk = t >> 5, o = t & 31;
    float add = 0.f;
    #pragma unroll
    for (int j = 0; j < 32; ++j) add += w1sm[o * 32 + j] * xs[tk * 32 + j];
    hst[(tk * 32 + o) * 17 + 0] += add;
  }
  __syncthreads();

  for (int tk = 0; tk < 8; ++tk) {
    const float* h1b = &hst[(tk * 32 + og) * 17];
    const float* h2b = &hst[(tk * 32 + 16 + og) * 17];
    float gacc = 0.f;
    #pragma unroll
    for (int i = 0; i < 16; ++i) {
      int j = (int)((jpack >> (4 * i)) & 15ull);
      float val = h1b[i] * h2b[j];
      float sv = ((spack >> i) & 1) ? -val : val;
      gacc += ((skipm >> i) & 1) ? 0.f : sv;
    }
    float gp0 = __shfl(gacc, (int)(t & 48), 64);
    gst[(tk * 16 + og) * 17 + a] = gacc * gelu_tanh(gp0);
  }
  {
    int tk = t >> 5, o32 = t & 31;
    shst[tk * 32 + o32] = hsst[tk * 64 + o32] * gelu_tanh(hsst[tk * 64 + 32 + o32]);
  }
  __syncthreads();

  {
    float wg2[16], wp2[16];
    #pragma unroll
    for (int i = 0; i < 16; ++i) {
      wg2[i] = w2mv[og * 144 + i * 9 + g];
      wp2[i] = w2mv[og * 144 + i * 9 + 4 + g];
    }
    for (int tk = 0; tk < 8; ++tk) {
      float y = 0.f;
      #pragma unroll
      for (int i = 0; i < 16; ++i) y += wg2[i] * gst[(tk * 16 + i) * 17 + a];
      if (pr >= 0) {
        #pragma unroll
        for (int i = 0; i < 16; ++i) y += wp2[i] * gst[(tk * 16 + i) * 17 + pr];
      }
      y2st[(tk * 16 + og) * 17 + a] = y;
    }
  }
  __syncthreads();

  if (t < 128) {
    int tk = t >> 4, o = t & 15;
    float add = 0.f;
    #pragma unroll
    for (int j = 0; j < 32; ++j) add += w2sm[o * 32 + j] * shst[tk * 32 + j];
    y2st[(tk * 16 + o) * 17 + 0] += add;
  }
  {
    int tk = t >> 5, o32 = t & 31;
    float ys = 0.f;
    #pragma unroll
    for (int j = 0; j < 32; ++j) ys += w2ss[o32 * 32 + j] * shst[tk * 32 + j];
    #pragma unroll
    for (int i = 0; i < 16; ++i) ys += w2ms[o32 * 16 + i] * gst[(tk * 16 + i) * 17 + 0];
    s[(size_t)(tok0 + tk) * 32 + o32] += ys;
  }
  __syncthreads();

  #pragma unroll
  for (int p = 0; p < 8; ++p) {
    int flat = p * 256 + t;
    int tk = flat >> 8, rem = flat & 255, o = rem >> 4, a2 = rem & 15;
    mv[(size_t)tok0 * 256 + flat] += y2st[(tk * 16 + o) * 17 + a2];
  }
}

// ---------------- final projection + mean ----------------
__global__ void __launch_bounds__(256) k_final(
    const float* __restrict__ mv, const float* __restrict__ s,
    const float* __restrict__ wout_mv, const float* __restrict__ wout_sm,
    float* __restrict__ out)
{
  __shared__ float red[256];
  int b = blockIdx.x, t = threadIdx.x;
  float part = 0.f;
  for (int n = t; n < NN; n += 256) {
    const float* mvp = mv + ((size_t)(b * NN + n) * 16) * 16;
    const float* sp = s + (size_t)(b * NN + n) * 32;
    float acc = 0.f;
    #pragma unroll
    for (int i = 0; i < 16; ++i) acc += wout_mv[i * 9] * mvp[i * 16];
    #pragma unroll
    for (int j = 0; j < 32; ++j) acc += wout_sm[j] * sp[j];
    part += acc;
  }
  red[t] = part;
  __syncthreads();
  for (int w = 128; w > 0; w >>= 1) { if (t < w) red[t] += red[t + w]; __syncthreads(); }
  if (t == 0) out[b] = red[0] / (float)NN;
}

extern "C" void kernel_launch(void* const* d_in, const int* in_sizes, int n_in,
                              void* d_out, int out_size, void* d_ws, size_t ws_size,
                              hipStream_t stream) {
  const float* inputs    = (const float*)d_in[0];
  const float* win_mv    = (const float*)d_in[1];
  const float* win_ms    = (const float*)d_in[2];
  const float* win_bs    = (const float*)d_in[3];
  const float* a_qkv_wmv = (const float*)d_in[4];
  const float* a_qkv_wsm = (const float*)d_in[5];
  const float* a_qkv_wms = (const float*)d_in[6];
  const float* a_qkv_wss = (const float*)d_in[7];
  const float* a_out_wmv = (const float*)d_in[8];
  const float* a_out_wsm = (const float*)d_in[9];
  const float* a_out_wms = (const float*)d_in[10];
  const float* a_out_wss = (const float*)d_in[11];
  const float* m1_wmv    = (const float*)d_in[12];
  const float* m1_wsm    = (const float*)d_in[13];
  const float* m1_wms    = (const float*)d_in[14];
  const float* m1_wss    = (const float*)d_in[15];
  const float* m2_wmv    = (const float*)d_in[16];
  const float* m2_wsm    = (const float*)d_in[17];
  const float* m2_wms    = (const float*)d_in[18];
  const float* m2_wss    = (const float*)d_in[19];
  const float* wout_mv   = (const float*)d_in[20];
  const float* wout_sm   = (const float*)d_in[21];
  float* out = (float*)d_out;

  float* ws = (float*)d_ws;
  float* mv    = ws;                    // 2097152 f
  float* s     = mv + 2097152;          // 262144 f
  float* o_mvA = s + 262144;            // A: o_mv 2097152 + o_s 262144
  float* lA    = o_mvA + 2 * 2359296;   // after A and B partial blocks: 2x65536
  ushort_t* q_bf = (ushort_t*)(lA + 2 * 65536);  // 2097152 bf16
  ushort_t* k_bf = q_bf + 2097152;               // 2097152 bf16
  ushort_t* vT   = k_bf + 2097152;               // 3145728 bf16
  // total: 2097152+262144 + 2*2359296 + 131072 + (7340032/2) = ~43.5 MB

  int ntok = BB * NN;
  int ntile = ntok / 8;  // 1024
  k_embed<<<ntok, 256, 0, stream>>>(inputs, win_mv, win_ms, win_bs, mv, s);

  for (int l = 0; l < LLAYERS; ++l) {
    k_ln_qkv<<<ntile, 256, 0, stream>>>(mv, s,
        a_qkv_wmv + (size_t)l * 48 * 16 * 9, a_qkv_wsm + (size_t)l * 48 * 32,
        a_qkv_wms + (size_t)l * 96 * 16,     a_qkv_wss + (size_t)l * 96 * 32,
        q_bf, k_bf, vT);
    k_attn<<<2048, 256, 0, stream>>>(q_bf, k_bf, vT, o_mvA, lA);
    k_out_res<<<ntile, 256, 0, stream>>>(o_mvA, lA,
        a_out_wmv + (size_t)l * 16 * 16 * 9, a_out_wsm + (size_t)l * 16 * 32,
        a_out_wms + (size_t)l * 32 * 16,     a_out_wss + (size_t)l * 32 * 32,
        mv, s);
    k_mlp_res<<<ntile, 256, 0, stream>>>(mv, s,
        m1_wmv + (size_t)l * 32 * 16 * 9, m1_wsm + (size_t)l * 32 * 32,
        m1_wms + (size_t)l * 64 * 16,     m1_wss + (size_t)l * 64 * 32,
        m2_wmv + (size_t)l * 16 * 16 * 9, m2_wsm + (size_t)l * 16 * 32,
        m2_wms + (size_t)l * 32 * 16,     m2_wss + (size_t)l * 32 * 32);
  }

  k_final<<<BB, 256, 0, stream>>>(mv, s, wout_mv, wout_sm, out);

  (void)in_sizes; (void)n_in; (void)out_size; (void)ws_size;
}

// Round 7
// 1020.954 us; speedup vs baseline: 1.2788x; 1.2594x over previous
//
#include <hip/hip_runtime.h>
#include <math.h>

#define BB 8
#define NN 1024
#define LLAYERS 8

typedef unsigned short ushort_t;
typedef unsigned int uint_t;
using bf16x8 = __attribute__((ext_vector_type(8))) short;
using f32x4  = __attribute__((ext_vector_type(4))) float;

__constant__ int d_GRADE[16] = {0,1,1,1,1,2,2,2,2,2,2,3,3,3,3,4};
__constant__ int d_PAIR[16]  = {-1,0,-1,-1,-1,2,3,4,-1,-1,-1,8,9,10,-1,14};
__constant__ int d_IB[8] = {0,2,3,4,8,9,10,14};
__constant__ int d_I2M[16] = {0,1,2,4,8,3,5,9,6,10,12,7,11,13,14,15};
__constant__ int d_M2I[16] = {0,1,2,5,3,6,8,11,4,7,9,12,10,13,14,15};

#define QSCALE (0.22360679774997896f * 1.4426950408889634f)

// gelu(x)=0.5x(1+tanh(y)) = x/(1+exp(-2y)), y=0.79788456(x+0.044715x^3)
__device__ __forceinline__ float gelu_tanh(float x) {
  float y = 0.7978845608028654f * (x + 0.044715f * x * x * x);
  float e2 = __builtin_amdgcn_exp2f(y * -2.8853900817779268f);
  return x * __builtin_amdgcn_rcpf(1.0f + e2);
}

__device__ __forceinline__ ushort_t f2b(float f) {
  union { float f; unsigned int u; } x;
  x.f = f;
  unsigned int r = x.u + 0x7fffu + ((x.u >> 16) & 1u);  // RNE
  return (ushort_t)(r >> 16);
}

// ---------------- embed ----------------
__global__ void __launch_bounds__(256) k_embed(
    const float* __restrict__ inp, const float* __restrict__ win_mv,
    const float* __restrict__ win_ms, const float* __restrict__ win_bs,
    float* __restrict__ mv, float* __restrict__ s)
{
  int tok = blockIdx.x, t = threadIdx.x;
  float x = inp[tok * 3 + 0];
  float y = inp[tok * 3 + 1];
  float z = inp[tok * 3 + 2];
  int o = t >> 4, aa = t & 15;
  float ma = (aa == 14) ? 1.f : (aa == 13) ? -x : (aa == 12) ? y : (aa == 11) ? -z : 0.f;
  int g = d_GRADE[aa];
  float val = win_mv[o * 9 + g] * ma;
  int pr = d_PAIR[aa];
  if (pr >= 0) {
    float mp = (pr == 14) ? 1.f : 0.f;
    val += win_mv[o * 9 + 4 + g] * mp;
  }
  mv[(size_t)tok * 256 + t] = val;
  if (t < 32) s[(size_t)tok * 32 + t] = win_bs[t];
  (void)win_ms;
}

// ---------------- LN + QKV projection, 8-token tile ----------------
__global__ void __launch_bounds__(256) k_ln_qkv(
    const float* __restrict__ mv, const float* __restrict__ s,
    const float* __restrict__ wmv, const float* __restrict__ wsm,
    const float* __restrict__ wms, const float* __restrict__ wss,
    ushort_t* __restrict__ q_bf, ushort_t* __restrict__ k_bf, ushort_t* __restrict__ vT)
{
  __shared__ float pool[9600];
  float* xmv = pool;           // [8][256]
  float* xs  = pool + 2048;    // [8][32]
  float* yst = pool + 2304;    // [8][48] rows, stride 17
  float* sst = pool + 8832;    // [8][96]

  int t = threadIdx.x;
  int tok0 = blockIdx.x * 8;
  int b = tok0 >> 10, n0 = tok0 & 1023;
  int a = t & 15, og = t >> 4;
  int g = d_GRADE[a], pr = d_PAIR[a];

  float wgq[16], wpq[16], wgk[16], wpk[16], wgv[16], wpv[16];
  #pragma unroll
  for (int i = 0; i < 16; ++i) {
    wgq[i] = wmv[(og)      * 144 + i * 9 + g];
    wgk[i] = wmv[(16 + og) * 144 + i * 9 + g];
    wgv[i] = wmv[(32 + og) * 144 + i * 9 + g];
    wpq[i] = wmv[(og)      * 144 + i * 9 + 4 + g];
    wpk[i] = wmv[(16 + og) * 144 + i * 9 + 4 + g];
    wpv[i] = wmv[(32 + og) * 144 + i * 9 + 4 + g];
  }

  #pragma unroll
  for (int j = 0; j < 2; ++j)
    *(float4*)&xmv[t * 4 + j * 1024] = *(const float4*)&mv[(size_t)tok0 * 256 + t * 4 + j * 1024];
  if (t < 64)
    *(float4*)&xs[t * 4] = *(const float4*)&s[(size_t)tok0 * 32 + t * 4];
  __syncthreads();

  if (t < 128) {
    int tk = t >> 4, ch = t & 15;
    float* xp = &xmv[tk * 256 + ch * 16];
    float4 v0 = *(float4*)&xp[0], v1 = *(float4*)&xp[4];
    float4 v2 = *(float4*)&xp[8], v3 = *(float4*)&xp[12];
    float ss = v0.x*v0.x + v0.z*v0.z + v0.w*v0.w + v1.x*v1.x
             + v2.x*v2.x + v2.y*v2.y + v2.z*v2.z + v3.z*v3.z;
    ss += __shfl_xor(ss, 1); ss += __shfl_xor(ss, 2);
    ss += __shfl_xor(ss, 4); ss += __shfl_xor(ss, 8);
    float inv = rsqrtf(ss / 16.f + 1e-6f);
    v0.x*=inv; v0.y*=inv; v0.z*=inv; v0.w*=inv;
    v1.x*=inv; v1.y*=inv; v1.z*=inv; v1.w*=inv;
    v2.x*=inv; v2.y*=inv; v2.z*=inv; v2.w*=inv;
    v3.x*=inv; v3.y*=inv; v3.z*=inv; v3.w*=inv;
    *(float4*)&xp[0] = v0; *(float4*)&xp[4] = v1;
    *(float4*)&xp[8] = v2; *(float4*)&xp[12] = v3;
    float s0 = xs[tk * 32 + ch * 2], s1 = xs[tk * 32 + ch * 2 + 1];
    float s2 = s0 * s0 + s1 * s1;
    s2 += __shfl_xor(s2, 1); s2 += __shfl_xor(s2, 2);
    s2 += __shfl_xor(s2, 4); s2 += __shfl_xor(s2, 8);
    float sinv = rsqrtf(s2 / 32.f + 1e-6f);
    xs[tk * 32 + ch * 2] = s0 * sinv;
    xs[tk * 32 + ch * 2 + 1] = s1 * sinv;
  }
  __syncthreads();

  for (int tk = 0; tk < 8; ++tk) {
    float y0 = 0.f, y1 = 0.f, y2 = 0.f;
    const float* xb = &xmv[tk * 256];
    #pragma unroll
    for (int i = 0; i < 16; ++i) {
      float xa_ = xb[i * 16 + a];
      y0 += wgq[i] * xa_; y1 += wgk[i] * xa_; y2 += wgv[i] * xa_;
    }
    if (pr >= 0) {
      #pragma unroll
      for (int i = 0; i < 16; ++i) {
        float xp_ = xb[i * 16 + pr];
        y0 += wpq[i] * xp_; y1 += wpk[i] * xp_; y2 += wpv[i] * xp_;
      }
    }
    yst[(tk * 48 + og) * 17 + a] = y0;
    yst[(tk * 48 + 16 + og) * 17 + a] = y1;
    yst[(tk * 48 + 32 + og) * 17 + a] = y2;
  }
  __syncthreads();

  for (int u = t; u < 384; u += 256) {
    int tk = u / 48, o = u % 48;
    float add = 0.f;
    #pragma unroll
    for (int j = 0; j < 32; ++j) add += wsm[o * 32 + j] * xs[tk * 32 + j];
    yst[(tk * 48 + o) * 17 + 0] += add;
  }
  for (int u = t; u < 768; u += 256) {
    int tk = u / 96, o96 = u % 96;
    float yy = 0.f;
    #pragma unroll
    for (int j = 0; j < 32; ++j) yy += wss[o96 * 32 + j] * xs[tk * 32 + j];
    #pragma unroll
    for (int i = 0; i < 16; ++i) yy += wms[o96 * 16 + i] * xmv[tk * 256 + i * 16];
    sst[tk * 96 + o96] = yy;
  }
  __syncthreads();

  if (t < 128) {
    int isK = t >> 6;
    int r = t & 63;
    int tk = r >> 3, h = r & 7;
    float scale = isK ? 1.f : QSCALE;
    const float* base = &yst[(tk * 48 + isK * 16) * 17];
    ushort_t tmp[32];
    #pragma unroll
    for (int j = 0; j < 8; ++j) {
      int blade = d_IB[j];
      tmp[j]     = f2b(base[(2 * h)     * 17 + blade] * scale);
      tmp[8 + j] = f2b(base[(2 * h + 1) * 17 + blade] * scale);
    }
    #pragma unroll
    for (int d = 0; d < 4; ++d)
      tmp[16 + d] = f2b(sst[tk * 96 + isK * 32 + h * 4 + d] * scale);
    #pragma unroll
    for (int j2 = 20; j2 < 32; ++j2) tmp[j2] = 0;
    uint_t out[16];
    #pragma unroll
    for (int j3 = 0; j3 < 16; ++j3)
      out[j3] = (uint_t)tmp[2 * j3] | ((uint_t)tmp[2 * j3 + 1] << 16);
    ushort_t* dst = (isK ? k_bf : q_bf) + ((size_t)(b * 8 + h) * 1024 + n0 + tk) * 32;
    *(uint4*)(dst +  0) = make_uint4(out[0],  out[1],  out[2],  out[3]);
    *(uint4*)(dst +  8) = make_uint4(out[4],  out[5],  out[6],  out[7]);
    *(uint4*)(dst + 16) = make_uint4(out[8],  out[9],  out[10], out[11]);
    *(uint4*)(dst + 24) = make_uint4(out[12], out[13], out[14], out[15]);
  }
  {
    int h = t >> 5, dim = t & 31;
    int ch = 2 * h + (dim >> 4), blade = dim & 15;
    uint_t ov[4];
    #pragma unroll
    for (int tk = 0; tk < 8; ++tk) {
      ushort_t bv = f2b(yst[(tk * 48 + 32 + ch) * 17 + blade]);
      if (tk & 1) ov[tk >> 1] |= ((uint_t)bv) << 16; else ov[tk >> 1] = bv;
    }
    ushort_t* dst = vT + ((size_t)(b * 8 + h) * 48 + dim) * 1024 + n0;
    *(uint4*)dst = make_uint4(ov[0], ov[1], ov[2], ov[3]);
  }
  if (t < 32) {
    int h = t >> 2, d = t & 3;
    uint_t ov[4];
    #pragma unroll
    for (int tk = 0; tk < 8; ++tk) {
      ushort_t bv = f2b(sst[tk * 96 + 64 + h * 4 + d]);
      if (tk & 1) ov[tk >> 1] |= ((uint_t)bv) << 16; else ov[tk >> 1] = bv;
    }
    ushort_t* dst = vT + ((size_t)(b * 8 + h) * 48 + 32 + d) * 1024 + n0;
    *(uint4*)dst = make_uint4(ov[0], ov[1], ov[2], ov[3]);
  }
  if (t < 8) {
    ushort_t* dst = vT + ((size_t)(b * 8 + t) * 48 + 36) * 1024 + n0;
    *(uint4*)dst = make_uint4(0x3F803F80u, 0x3F803F80u, 0x3F803F80u, 0x3F803F80u);
  }
}

// ---------------- attention: bf16 MFMA, no-max softmax, key-split x2 ---------------
// NEW: block-level LDS staging of K/V — each cache line requested ONCE per block
// instead of once per wave (4x fewer TA line-requests, the measured R4-R6 wall).
#define OPART_STRIDE 2359296   // floats between A and B partial o_mv/o_s blocks
#define LPART_STRIDE 65536
__global__ void __launch_bounds__(256) k_attn(
    const ushort_t* __restrict__ q_bf, const ushort_t* __restrict__ k_bf,
    const ushort_t* __restrict__ vT, float* __restrict__ o_mvA, float* __restrict__ lA)
{
  // K tile: 64 keys x 32 dims, row stride 40 ushorts (80B, 16B-aligned, 2-way banks)
  // V tile: rows 0..36 staged (37..47 never consumed), row stride 72 ushorts (144B)
  __shared__ __align__(16) ushort_t kst[64 * 40];
  __shared__ __align__(16) ushort_t vst[48 * 72];
  __shared__ __align__(16) ushort_t plds[4][1280];
  int bx = blockIdx.x;
  int bh = bx & 63, qg = bx >> 6;
  int qb = qg & 15, kg = qg >> 4;
  int b = bh >> 3, h = bh & 7;
  int t = threadIdx.x;
  int w = t >> 6, lane = t & 63;
  int quad = lane >> 4, col = lane & 15;
  int q16 = qb * 64 + w * 16;
  size_t hb = (size_t)bh * 1024;
  ushort_t* myp = &plds[w][0];

  float* o_mvp = o_mvA + (size_t)kg * OPART_STRIDE;
  float* o_sp  = o_mvp + 2097152;
  float* l_p   = lA + (size_t)kg * LPART_STRIDE;

  bf16x8 qfrag = *(const bf16x8*)(q_bf + (hb + q16 + col) * 32 + quad * 8);

  f32x4 ot0 = {0.f,0.f,0.f,0.f}, ot1 = {0.f,0.f,0.f,0.f}, ot2 = {0.f,0.f,0.f,0.f};

  const ushort_t* kbase = k_bf + hb * 32;
  const ushort_t* vbase = vT + (size_t)bh * 48 * 1024;
  int k0 = kg * 512;

  // staging indices (loop-invariant)
  int skey = t >> 2, sc4 = t & 3;          // K: 64 keys x 4 16B-chunks
  for (int kt = 0; kt < 8; ++kt) {
    int kb = k0 + kt * 64;
    __syncthreads();  // all waves done reading previous tile
    *(uint4*)&kst[skey * 40 + sc4 * 8] =
        *(const uint4*)(kbase + (size_t)(kb + skey) * 32 + sc4 * 8);
    for (int u = t; u < 296; u += 256) {   // V rows 0..36 x 8 16B-chunks
      int row = u >> 3, c8 = u & 7;
      *(uint4*)&vst[row * 72 + c8 * 8] =
          *(const uint4*)(vbase + (size_t)row * 1024 + kb + c8 * 8);
    }
    __syncthreads();

    bf16x8 sk0 = *(const bf16x8*)&kst[(     col) * 40 + quad * 8];
    bf16x8 sk1 = *(const bf16x8*)&kst[(16 + col) * 40 + quad * 8];
    bf16x8 sk2 = *(const bf16x8*)&kst[(32 + col) * 40 + quad * 8];
    bf16x8 sk3 = *(const bf16x8*)&kst[(48 + col) * 40 + quad * 8];
    bf16x8 va0 = *(const bf16x8*)&vst[(     col) * 72 + quad * 8];
    bf16x8 va1 = *(const bf16x8*)&vst[(16 + col) * 72 + quad * 8];
    bf16x8 va2 = *(const bf16x8*)&vst[(32 + col) * 72 + quad * 8];
    bf16x8 vb0 = *(const bf16x8*)&vst[(     col) * 72 + 32 + quad * 8];
    bf16x8 vb1 = *(const bf16x8*)&vst[(16 + col) * 72 + 32 + quad * 8];
    bf16x8 vb2 = *(const bf16x8*)&vst[(32 + col) * 72 + 32 + quad * 8];
    f32x4 zero = {0.f,0.f,0.f,0.f};
    f32x4 sa0 = __builtin_amdgcn_mfma_f32_16x16x32_bf16(sk0, qfrag, zero, 0, 0, 0);
    f32x4 sa1 = __builtin_amdgcn_mfma_f32_16x16x32_bf16(sk1, qfrag, zero, 0, 0, 0);
    f32x4 sb0 = __builtin_amdgcn_mfma_f32_16x16x32_bf16(sk2, qfrag, zero, 0, 0, 0);
    f32x4 sb1 = __builtin_amdgcn_mfma_f32_16x16x32_bf16(sk3, qfrag, zero, 0, 0, 0);

    union { float f; uint_t u; } e0, e1, e2, e3;
    e0.f = __builtin_amdgcn_exp2f(sa0[0]); e1.f = __builtin_amdgcn_exp2f(sa0[1]);
    e2.f = __builtin_amdgcn_exp2f(sa0[2]); e3.f = __builtin_amdgcn_exp2f(sa0[3]);
    uint_t a0 = __builtin_amdgcn_perm(e1.u, e0.u, 0x07060302u);
    uint_t a1 = __builtin_amdgcn_perm(e3.u, e2.u, 0x07060302u);
    e0.f = __builtin_amdgcn_exp2f(sa1[0]); e1.f = __builtin_amdgcn_exp2f(sa1[1]);
    e2.f = __builtin_amdgcn_exp2f(sa1[2]); e3.f = __builtin_amdgcn_exp2f(sa1[3]);
    uint_t a2 = __builtin_amdgcn_perm(e1.u, e0.u, 0x07060302u);
    uint_t a3 = __builtin_amdgcn_perm(e3.u, e2.u, 0x07060302u);
    e0.f = __builtin_amdgcn_exp2f(sb0[0]); e1.f = __builtin_amdgcn_exp2f(sb0[1]);
    e2.f = __builtin_amdgcn_exp2f(sb0[2]); e3.f = __builtin_amdgcn_exp2f(sb0[3]);
    uint_t b0 = __builtin_amdgcn_perm(e1.u, e0.u, 0x07060302u);
    uint_t b1 = __builtin_amdgcn_perm(e3.u, e2.u, 0x07060302u);
    e0.f = __builtin_amdgcn_exp2f(sb1[0]); e1.f = __builtin_amdgcn_exp2f(sb1[1]);
    e2.f = __builtin_amdgcn_exp2f(sb1[2]); e3.f = __builtin_amdgcn_exp2f(sb1[3]);
    uint_t b2 = __builtin_amdgcn_perm(e1.u, e0.u, 0x07060302u);
    uint_t b3 = __builtin_amdgcn_perm(e3.u, e2.u, 0x07060302u);

    *(uint2*)(myp + col * 40 + quad * 4)            = make_uint2(a0, a1);
    *(uint2*)(myp + col * 40 + 16 + quad * 4)       = make_uint2(a2, a3);
    *(uint2*)(myp + 640 + col * 40 + quad * 4)      = make_uint2(b0, b1);
    *(uint2*)(myp + 640 + col * 40 + 16 + quad * 4) = make_uint2(b2, b3);
    __builtin_amdgcn_wave_barrier();
    bf16x8 pfa = *(const bf16x8*)(myp + col * 40 + quad * 8);
    bf16x8 pfb = *(const bf16x8*)(myp + 640 + col * 40 + quad * 8);
    __builtin_amdgcn_wave_barrier();
    ot0 = __builtin_amdgcn_mfma_f32_16x16x32_bf16(va0, pfa, ot0, 0, 0, 0);
    ot1 = __builtin_amdgcn_mfma_f32_16x16x32_bf16(va1, pfa, ot1, 0, 0, 0);
    ot2 = __builtin_amdgcn_mfma_f32_16x16x32_bf16(va2, pfa, ot2, 0, 0, 0);
    ot0 = __builtin_amdgcn_mfma_f32_16x16x32_bf16(vb0, pfb, ot0, 0, 0, 0);
    ot1 = __builtin_amdgcn_mfma_f32_16x16x32_bf16(vb1, pfb, ot1, 0, 0, 0);
    ot2 = __builtin_amdgcn_mfma_f32_16x16x32_bf16(vb2, pfb, ot2, 0, 0, 0);
  }

  int tok = b * NN + q16 + col;
  float* op0 = o_mvp + (size_t)tok * 256 + (2 * h) * 16 + quad * 4;
  op0[0] = ot0[0]; op0[1] = ot0[1]; op0[2] = ot0[2]; op0[3] = ot0[3];
  float* op1 = o_mvp + (size_t)tok * 256 + (2 * h + 1) * 16 + quad * 4;
  op1[0] = ot1[0]; op1[1] = ot1[1]; op1[2] = ot1[2]; op1[3] = ot1[3];
  if (quad == 0) {
    float* osp = o_sp + (size_t)tok * 32 + h * 4;
    osp[0] = ot2[0]; osp[1] = ot2[1]; osp[2] = ot2[2]; osp[3] = ot2[3];
  }
  if (quad == 1) l_p[hb + q16 + col] = ot2[0];
}

// ---------------- attention combine + out-proj + residual, 8-token tile ----------------
__global__ void __launch_bounds__(256) k_out_res(
    const float* __restrict__ o_mvA, const float* __restrict__ lA,
    const float* __restrict__ wmv, const float* __restrict__ wsm,
    const float* __restrict__ wms, const float* __restrict__ wss,
    float* __restrict__ mv, float* __restrict__ s)
{
  __shared__ float pool[4544];
  float* xo    = pool;          // [8][256]
  float* xso   = pool + 2048;   // [8][32]
  float* yst   = pool + 2304;   // [8][16] rows, stride 17
  float* invls = pool + 4480;   // [8][8]

  const float* o_sA  = o_mvA + 2097152;
  const float* o_mvB = o_mvA + OPART_STRIDE;
  const float* o_sB  = o_mvB + 2097152;
  const float* lB    = lA + LPART_STRIDE;

  int t = threadIdx.x;
  int tok0 = blockIdx.x * 8;
  int b8 = (tok0 >> 10) * 8, n0 = tok0 & 1023;
  int a = t & 15, og = t >> 4;
  int g = d_GRADE[a], pr = d_PAIR[a];

  float wg[16], wp[16];
  #pragma unroll
  for (int i = 0; i < 16; ++i) {
    wg[i] = wmv[og * 144 + i * 9 + g];
    wp[i] = wmv[og * 144 + i * 9 + 4 + g];
  }

  float4 ra[2], rc[2];
  #pragma unroll
  for (int j = 0; j < 2; ++j) {
    ra[j] = *(const float4*)&o_mvA[(size_t)tok0 * 256 + t * 4 + j * 1024];
    rc[j] = *(const float4*)&o_mvB[(size_t)tok0 * 256 + t * 4 + j * 1024];
  }
  float4 sa4 = {0,0,0,0}, sc4 = {0,0,0,0};
  if (t < 64) {
    int tk = t >> 3, h = t & 7;
    sa4 = *(const float4*)&o_sA[(size_t)(tok0 + tk) * 32 + h * 4];
    sc4 = *(const float4*)&o_sB[(size_t)(tok0 + tk) * 32 + h * 4];
    float la = lA[(size_t)(b8 + h) * 1024 + n0 + tk];
    float lb = lB[(size_t)(b8 + h) * 1024 + n0 + tk];
    invls[t] = 1.f / (la + lb);
  }
  __syncthreads();

  #pragma unroll
  for (int j = 0; j < 2; ++j) {
    int idx = t * 4 + j * 1024;
    int tk = idx >> 8, o = (idx >> 4) & 15;
    float il = invls[tk * 8 + (o >> 1)];
    xo[idx + 0] = (ra[j].x + rc[j].x) * il;
    xo[idx + 1] = (ra[j].y + rc[j].y) * il;
    xo[idx + 2] = (ra[j].z + rc[j].z) * il;
    xo[idx + 3] = (ra[j].w + rc[j].w) * il;
  }
  if (t < 64) {
    int tk = t >> 3, h = t & 7;
    float il = invls[t];
    xso[tk * 32 + h * 4 + 0] = (sa4.x + sc4.x) * il;
    xso[tk * 32 + h * 4 + 1] = (sa4.y + sc4.y) * il;
    xso[tk * 32 + h * 4 + 2] = (sa4.z + sc4.z) * il;
    xso[tk * 32 + h * 4 + 3] = (sa4.w + sc4.w) * il;
  }
  __syncthreads();

  for (int tk = 0; tk < 8; ++tk) {
    float y = 0.f;
    const float* xb = &xo[tk * 256];
    #pragma unroll
    for (int i = 0; i < 16; ++i) y += wg[i] * xb[i * 16 + a];
    if (pr >= 0) {
      #pragma unroll
      for (int i = 0; i < 16; ++i) y += wp[i] * xb[i * 16 + pr];
    }
    yst[(tk * 16 + og) * 17 + a] = y;
  }
  __syncthreads();

  if (t < 128) {
    int tk = t >> 4, o = t & 15;
    float add = 0.f;
    #pragma unroll
    for (int j = 0; j < 32; ++j) add += wsm[o * 32 + j] * xso[tk * 32 + j];
    yst[(tk * 16 + o) * 17 + 0] += add;
  }
  {
    int o32 = t & 31, tk = t >> 5;
    float ys = 0.f;
    #pragma unroll
    for (int j = 0; j < 32; ++j) ys += wss[o32 * 32 + j] * xso[tk * 32 + j];
    #pragma unroll
    for (int i = 0; i < 16; ++i) ys += wms[o32 * 16 + i] * xo[tk * 256 + i * 16];
    s[(size_t)(tok0 + tk) * 32 + o32] += ys;
  }
  __syncthreads();

  #pragma unroll
  for (int p = 0; p < 8; ++p) {
    int flat = p * 256 + t;
    int tk = flat >> 8, rem = flat & 255, o = rem >> 4, a2 = rem & 15;
    mv[(size_t)tok0 * 256 + flat] += yst[(tk * 16 + o) * 17 + a2];
  }
}

// ---------------- LN + geometric MLP + residual, 8-token tile ----------------
__global__ void __launch_bounds__(256) k_mlp_res(
    float* __restrict__ mv, float* __restrict__ s,
    const float* __restrict__ w1mv, const float* __restrict__ w1sm,
    const float* __restrict__ w1ms, const float* __restrict__ w1ss,
    const float* __restrict__ w2mv, const float* __restrict__ w2sm,
    const float* __restrict__ w2ms, const float* __restrict__ w2ss)
{
  __shared__ float pool[9600];
  float* xmv  = pool;           // [8][256]
  float* xs   = pool + 2048;    // [8][32]
  float* hst  = pool + 2304;    // [8][32] rows, stride 17
  float* y2st = pool + 2304;    // alias of hst (dead when reused)
  float* hsst = pool + 6656;    // [8][64]
  float* gst  = pool + 7168;    // [8][16] rows, stride 17
  float* shst = pool + 9344;    // [8][32]

  int t = threadIdx.x;
  int tok0 = blockIdx.x * 8;
  int a = t & 15, og = t >> 4;
  int g = d_GRADE[a], pr = d_PAIR[a];

  unsigned long long jpack = 0; unsigned int spack = 0, skipm = 0;
  {
    int mk = d_I2M[a];
    for (int i = 0; i < 16; ++i) {
      int mi = d_I2M[i];
      int mj = mi ^ mk;
      if (mi & mj & 1) { skipm |= 1u << i; continue; }
      int j = d_M2I[mj];
      int sw = 0;
      for (int bb2 = 0; bb2 < 4; ++bb2)
        if (mj & (1 << bb2)) sw += __popc(((unsigned)mi) >> (bb2 + 1));
      jpack |= (unsigned long long)j << (4 * i);
      spack |= (unsigned)(sw & 1) << i;
    }
  }

  float wg1a[16], wp1a[16], wg1b[16], wp1b[16];
  #pragma unroll
  for (int i = 0; i < 16; ++i) {
    wg1a[i] = w1mv[(og)      * 144 + i * 9 + g];
    wg1b[i] = w1mv[(16 + og) * 144 + i * 9 + g];
    wp1a[i] = w1mv[(og)      * 144 + i * 9 + 4 + g];
    wp1b[i] = w1mv[(16 + og) * 144 + i * 9 + 4 + g];
  }

  #pragma unroll
  for (int j = 0; j < 2; ++j)
    *(float4*)&xmv[t * 4 + j * 1024] = *(const float4*)&mv[(size_t)tok0 * 256 + t * 4 + j * 1024];
  if (t < 64)
    *(float4*)&xs[t * 4] = *(const float4*)&s[(size_t)tok0 * 32 + t * 4];
  __syncthreads();

  if (t < 128) {
    int tk = t >> 4, ch = t & 15;
    float* xp = &xmv[tk * 256 + ch * 16];
    float4 v0 = *(float4*)&xp[0], v1 = *(float4*)&xp[4];
    float4 v2 = *(float4*)&xp[8], v3 = *(float4*)&xp[12];
    float ss = v0.x*v0.x + v0.z*v0.z + v0.w*v0.w + v1.x*v1.x
             + v2.x*v2.x + v2.y*v2.y + v2.z*v2.z + v3.z*v3.z;
    ss += __shfl_xor(ss, 1); ss += __shfl_xor(ss, 2);
    ss += __shfl_xor(ss, 4); ss += __shfl_xor(ss, 8);
    float inv = rsqrtf(ss / 16.f + 1e-6f);
    v0.x*=inv; v0.y*=inv; v0.z*=inv; v0.w*=inv;
    v1.x*=inv; v1.y*=inv; v1.z*=inv; v1.w*=inv;
    v2.x*=inv; v2.y*=inv; v2.z*=inv; v2.w*=inv;
    v3.x*=inv; v3.y*=inv; v3.z*=inv; v3.w*=inv;
    *(float4*)&xp[0] = v0; *(float4*)&xp[4] = v1;
    *(float4*)&xp[8] = v2; *(float4*)&xp[12] = v3;
    float s0 = xs[tk * 32 + ch * 2], s1 = xs[tk * 32 + ch * 2 + 1];
    float s2 = s0 * s0 + s1 * s1;
    s2 += __shfl_xor(s2, 1); s2 += __shfl_xor(s2, 2);
    s2 += __shfl_xor(s2, 4); s2 += __shfl_xor(s2, 8);
    float sinv = rsqrtf(s2 / 32.f + 1e-6f);
    xs[tk * 32 + ch * 2] = s0 * sinv;
    xs[tk * 32 + ch * 2 + 1] = s1 * sinv;
  }
  __syncthreads();

  for (int tk = 0; tk < 8; ++tk) {
    float y0 = 0.f, y1 = 0.f;
    const float* xb = &xmv[tk * 256];
    #pragma unroll
    for (int i = 0; i < 16; ++i) {
      float xa_ = xb[i * 16 + a];
      y0 += wg1a[i] * xa_; y1 += wg1b[i] * xa_;
    }
    if (pr >= 0) {
      #pragma unroll
      for (int i = 0; i < 16; ++i) {
        float xp_ = xb[i * 16 + pr];
        y0 += wp1a[i] * xp_; y1 += wp1b[i] * xp_;
      }
    }
    hst[(tk * 32 + og) * 17 + a] = y0;
    hst[(tk * 32 + 16 + og) * 17 + a] = y1;
  }
  for (int u = t; u < 512; u += 256) {
    int tk = u >> 6, o64 = u & 63;
    float yy = 0.f;
    #pragma unroll
    for (int j = 0; j < 32; ++j) yy += w1ss[o64 * 32 + j] * xs[tk * 32 + j];
    #pragma unroll
    for (int i = 0; i < 16; ++i) yy += w1ms[o64 * 16 + i] * xmv[tk * 256 + i * 16];
    hsst[tk * 64 + o64] = yy;
  }
  __syncthreads();

  {
    int tk = t >> 5, o = t & 31;
    float add = 0.f;
    #pragma unroll
    for (int j = 0; j < 32; ++j) add += w1sm[o * 32 + j] * xs[tk * 32 + j];
    hst[(tk * 32 + o) * 17 + 0] += add;
  }
  __syncthreads();

  for (int tk = 0; tk < 8; ++tk) {
    const float* h1b = &hst[(tk * 32 + og) * 17];
    const float* h2b = &hst[(tk * 32 + 16 + og) * 17];
    float gacc = 0.f;
    #pragma unroll
    for (int i = 0; i < 16; ++i) {
      int j = (int)((jpack >> (4 * i)) & 15ull);
      float val = h1b[i] * h2b[j];
      float sv = ((spack >> i) & 1) ? -val : val;
      gacc += ((skipm >> i) & 1) ? 0.f : sv;
    }
    float gp0 = __shfl(gacc, (int)(t & 48), 64);
    gst[(tk * 16 + og) * 17 + a] = gacc * gelu_tanh(gp0);
  }
  {
    int tk = t >> 5, o32 = t & 31;
    shst[tk * 32 + o32] = hsst[tk * 64 + o32] * gelu_tanh(hsst[tk * 64 + 32 + o32]);
  }
  __syncthreads();

  {
    float wg2[16], wp2[16];
    #pragma unroll
    for (int i = 0; i < 16; ++i) {
      wg2[i] = w2mv[og * 144 + i * 9 + g];
      wp2[i] = w2mv[og * 144 + i * 9 + 4 + g];
    }
    for (int tk = 0; tk < 8; ++tk) {
      float y = 0.f;
      #pragma unroll
      for (int i = 0; i < 16; ++i) y += wg2[i] * gst[(tk * 16 + i) * 17 + a];
      if (pr >= 0) {
        #pragma unroll
        for (int i = 0; i < 16; ++i) y += wp2[i] * gst[(tk * 16 + i) * 17 + pr];
      }
      y2st[(tk * 16 + og) * 17 + a] = y;
    }
  }
  __syncthreads();

  if (t < 128) {
    int tk = t >> 4, o = t & 15;
    float add = 0.f;
    #pragma unroll
    for (int j = 0; j < 32; ++j) add += w2sm[o * 32 + j] * shst[tk * 32 + j];
    y2st[(tk * 16 + o) * 17 + 0] += add;
  }
  {
    int tk = t >> 5, o32 = t & 31;
    float ys = 0.f;
    #pragma unroll
    for (int j = 0; j < 32; ++j) ys += w2ss[o32 * 32 + j] * shst[tk * 32 + j];
    #pragma unroll
    for (int i = 0; i < 16; ++i) ys += w2ms[o32 * 16 + i] * gst[(tk * 16 + i) * 17 + 0];
    s[(size_t)(tok0 + tk) * 32 + o32] += ys;
  }
  __syncthreads();

  #pragma unroll
  for (int p = 0; p < 8; ++p) {
    int flat = p * 256 + t;
    int tk = flat >> 8, rem = flat & 255, o = rem >> 4, a2 = rem & 15;
    mv[(size_t)tok0 * 256 + flat] += y2st[(tk * 16 + o) * 17 + a2];
  }
}

// ---------------- final projection + mean ----------------
__global__ void __launch_bounds__(256) k_final(
    const float* __restrict__ mv, const float* __restrict__ s,
    const float* __restrict__ wout_mv, const float* __restrict__ wout_sm,
    float* __restrict__ out)
{
  __shared__ float red[256];
  int b = blockIdx.x, t = threadIdx.x;
  float part = 0.f;
  for (int n = t; n < NN; n += 256) {
    const float* mvp = mv + ((size_t)(b * NN + n) * 16) * 16;
    const float* sp = s + (size_t)(b * NN + n) * 32;
    float acc = 0.f;
    #pragma unroll
    for (int i = 0; i < 16; ++i) acc += wout_mv[i * 9] * mvp[i * 16];
    #pragma unroll
    for (int j = 0; j < 32; ++j) acc += wout_sm[j] * sp[j];
    part += acc;
  }
  red[t] = part;
  __syncthreads();
  for (int w = 128; w > 0; w >>= 1) { if (t < w) red[t] += red[t + w]; __syncthreads(); }
  if (t == 0) out[b] = red[0] / (float)NN;
}

extern "C" void kernel_launch(void* const* d_in, const int* in_sizes, int n_in,
                              void* d_out, int out_size, void* d_ws, size_t ws_size,
                              hipStream_t stream) {
  const float* inputs    = (const float*)d_in[0];
  const float* win_mv    = (const float*)d_in[1];
  const float* win_ms    = (const float*)d_in[2];
  const float* win_bs    = (const float*)d_in[3];
  const float* a_qkv_wmv = (const float*)d_in[4];
  const float* a_qkv_wsm = (const float*)d_in[5];
  const float* a_qkv_wms = (const float*)d_in[6];
  const float* a_qkv_wss = (const float*)d_in[7];
  const float* a_out_wmv = (const float*)d_in[8];
  const float* a_out_wsm = (const float*)d_in[9];
  const float* a_out_wms = (const float*)d_in[10];
  const float* a_out_wss = (const float*)d_in[11];
  const float* m1_wmv    = (const float*)d_in[12];
  const float* m1_wsm    = (const float*)d_in[13];
  const float* m1_wms    = (const float*)d_in[14];
  const float* m1_wss    = (const float*)d_in[15];
  const float* m2_wmv    = (const float*)d_in[16];
  const float* m2_wsm    = (const float*)d_in[17];
  const float* m2_wms    = (const float*)d_in[18];
  const float* m2_wss    = (const float*)d_in[19];
  const float* wout_mv   = (const float*)d_in[20];
  const float* wout_sm   = (const float*)d_in[21];
  float* out = (float*)d_out;

  float* ws = (float*)d_ws;
  float* mv    = ws;                    // 2097152 f
  float* s     = mv + 2097152;          // 262144 f
  float* o_mvA = s + 262144;            // A: o_mv 2097152 + o_s 262144; B follows
  float* lA    = o_mvA + 2 * 2359296;   // 2 x 65536
  ushort_t* q_bf = (ushort_t*)(lA + 2 * 65536);  // 2097152 bf16
  ushort_t* k_bf = q_bf + 2097152;               // 2097152 bf16
  ushort_t* vT   = k_bf + 2097152;               // 3145728 bf16

  int ntok = BB * NN;
  int ntile = ntok / 8;  // 1024
  k_embed<<<ntok, 256, 0, stream>>>(inputs, win_mv, win_ms, win_bs, mv, s);

  for (int l = 0; l < LLAYERS; ++l) {
    k_ln_qkv<<<ntile, 256, 0, stream>>>(mv, s,
        a_qkv_wmv + (size_t)l * 48 * 16 * 9, a_qkv_wsm + (size_t)l * 48 * 32,
        a_qkv_wms + (size_t)l * 96 * 16,     a_qkv_wss + (size_t)l * 96 * 32,
        q_bf, k_bf, vT);
    k_attn<<<2048, 256, 0, stream>>>(q_bf, k_bf, vT, o_mvA, lA);
    k_out_res<<<ntile, 256, 0, stream>>>(o_mvA, lA,
        a_out_wmv + (size_t)l * 16 * 16 * 9, a_out_wsm + (size_t)l * 16 * 32,
        a_out_wms + (size_t)l * 32 * 16,     a_out_wss + (size_t)l * 32 * 32,
        mv, s);
    k_mlp_res<<<ntile, 256, 0, stream>>>(mv, s,
        m1_wmv + (size_t)l * 32 * 16 * 9, m1_wsm + (size_t)l * 32 * 32,
        m1_wms + (size_t)l * 64 * 16,     m1_wss + (size_t)l * 64 * 32,
        m2_wmv + (size_t)l * 16 * 16 * 9, m2_wsm + (size_t)l * 16 * 32,
        m2_wms + (size_t)l * 32 * 16,     m2_wss + (size_t)l * 32 * 32);
  }

  k_final<<<BB, 256, 0, stream>>>(mv, s, wout_mv, wout_sm, out);

  (void)in_sizes; (void)n_in; (void)out_size; (void)ws_size;
}